// Round 1
// baseline (1508.654 us; speedup 1.0000x reference)
//
#include <hip/hip_runtime.h>
#include <math.h>

#define BB 2
#define SS 2048
#define DD 1024
#define HH 16
#define HD 64
#define MM (BB*SS)   // 4096

// ---------------------------------------------------------------------------
// GEMM: C[M,D] = A[M,D] @ W[D,D] (+bias). PERMUTE: write [B,H,S,HD] layout.
// 64x64 tile, BK=16, 256 threads, 4x4 per thread. fp32 baseline.
// ---------------------------------------------------------------------------
template<bool PERMUTE, bool BIAS>
__global__ __launch_bounds__(256) void gemm_kernel(const float* __restrict__ A,
                                                   const float* __restrict__ W,
                                                   const float* __restrict__ bias,
                                                   float* __restrict__ Cout) {
    __shared__ float As[16][68];   // [k][row]
    __shared__ float Ws[16][68];   // [k][col]
    const int t  = threadIdx.x;
    const int tx = t % 16;
    const int ty = t / 16;
    const int col0 = blockIdx.x * 64;
    const int row0 = blockIdx.y * 64;
    float acc[4][4] = {};
    for (int k0 = 0; k0 < DD; k0 += 16) {
        {   // A tile: 64 rows x 16 k
            int c = t % 16;
            int r = t / 16;
            #pragma unroll
            for (int rr = 0; rr < 4; ++rr)
                As[c][r + rr*16] = A[(size_t)(row0 + r + rr*16)*DD + k0 + c];
        }
        {   // W tile: 16 k x 64 cols
            int c = t % 64;
            int r = t / 64;
            #pragma unroll
            for (int rr = 0; rr < 4; ++rr)
                Ws[r + rr*4][c] = W[(size_t)(k0 + r + rr*4)*DD + col0 + c];
        }
        __syncthreads();
        #pragma unroll
        for (int kk = 0; kk < 16; ++kk) {
            float a[4], b[4];
            #pragma unroll
            for (int i = 0; i < 4; ++i) a[i] = As[kk][ty*4 + i];
            #pragma unroll
            for (int j = 0; j < 4; ++j) b[j] = Ws[kk][tx*4 + j];
            #pragma unroll
            for (int i = 0; i < 4; ++i)
                #pragma unroll
                for (int j = 0; j < 4; ++j)
                    acc[i][j] = fmaf(a[i], b[j], acc[i][j]);
        }
        __syncthreads();
    }
    #pragma unroll
    for (int i = 0; i < 4; ++i) {
        int r = row0 + ty*4 + i;            // r = b*S + s
        #pragma unroll
        for (int j = 0; j < 4; ++j) {
            int c = col0 + tx*4 + j;        // c = h*64 + d
            float v = acc[i][j];
            if (BIAS) v += bias[c];
            if (PERMUTE) {
                int b_ = r / SS, s_ = r % SS;
                int h_ = c / HD, d_ = c % HD;
                Cout[(((size_t)b_*HH + h_)*SS + s_)*HD + d_] = v;
            } else {
                Cout[(size_t)r*DD + c] = v;
            }
        }
    }
}

// ---------------------------------------------------------------------------
// Causal flash attention. Block = (b, h, 64-row q tile), 256 threads.
// Thread t: row = t/4 (0..63), qd = t%4 (dims qd*16 .. qd*16+15).
// scores = (q.k) * 0.2, causal mask, online softmax, acc += p*V.
// ctx written in [B,S,D] layout.
// ---------------------------------------------------------------------------
__global__ __launch_bounds__(256) void attn_kernel(const float* __restrict__ Q,
                                                   const float* __restrict__ K,
                                                   const float* __restrict__ V,
                                                   float* __restrict__ ctx) {
    __shared__ float Ks[64][68];
    __shared__ float Vs[64][68];
    const int qt = blockIdx.x;          // 0..31
    const int h  = blockIdx.y;
    const int b  = blockIdx.z;
    const int t  = threadIdx.x;
    const int row = t / 4;
    const int qd  = t % 4;
    const size_t bh = ((size_t)b*HH + h)*SS;
    const int qg = qt*64 + row;

    float qreg[16];
    #pragma unroll
    for (int i = 0; i < 16; ++i) qreg[i] = Q[(bh + qg)*HD + qd*16 + i];

    float acc[16] = {};
    float m = -1e30f, l = 0.f;

    for (int kt = 0; kt <= qt; ++kt) {
        {   // stage K,V 64x64 tiles (1024 float4 each; 4 per thread)
            const float4* Kg = (const float4*)(K + (bh + (size_t)kt*64)*HD);
            const float4* Vg = (const float4*)(V + (bh + (size_t)kt*64)*HD);
            #pragma unroll
            for (int u = 0; u < 4; ++u) {
                int idx = t + u*256;        // 0..1023
                int kr = idx / 16;
                int kc = (idx % 16) * 4;
                *(float4*)&Ks[kr][kc] = Kg[idx];
                *(float4*)&Vs[kr][kc] = Vg[idx];
            }
        }
        __syncthreads();

        float sc[64];
        #pragma unroll
        for (int key = 0; key < 64; ++key) {
            float s = 0.f;
            #pragma unroll
            for (int i = 0; i < 16; ++i)
                s = fmaf(qreg[i], Ks[key][qd*16 + i], s);
            s += __shfl_xor(s, 1);
            s += __shfl_xor(s, 2);
            int kg = kt*64 + key;
            sc[key] = (kg <= qg) ? s * 0.2f : -1e30f;
        }
        float tmax = -1e30f;
        #pragma unroll
        for (int key = 0; key < 64; ++key) tmax = fmaxf(tmax, sc[key]);
        float mnew = fmaxf(m, tmax);
        float scale = __expf(m - mnew);
        float lsum = 0.f;
        #pragma unroll
        for (int key = 0; key < 64; ++key) {
            float p = __expf(sc[key] - mnew);
            sc[key] = p;
            lsum += p;
        }
        l = l*scale + lsum;
        m = mnew;
        #pragma unroll
        for (int i = 0; i < 16; ++i) acc[i] *= scale;
        #pragma unroll
        for (int key = 0; key < 64; ++key) {
            float p = sc[key];
            #pragma unroll
            for (int i = 0; i < 16; ++i)
                acc[i] = fmaf(p, Vs[key][qd*16 + i], acc[i]);
        }
        __syncthreads();
    }

    float inv = 1.f / l;
    #pragma unroll
    for (int u = 0; u < 4; ++u) {
        float4 o;
        o.x = acc[u*4 + 0] * inv;
        o.y = acc[u*4 + 1] * inv;
        o.z = acc[u*4 + 2] * inv;
        o.w = acc[u*4 + 3] * inv;
        *(float4*)&ctx[((size_t)b*SS + qg)*DD + h*HD + qd*16 + u*4] = o;
    }
}

extern "C" void kernel_launch(void* const* d_in, const int* in_sizes, int n_in,
                              void* d_out, int out_size, void* d_ws, size_t ws_size,
                              hipStream_t stream) {
    const float* x  = (const float*)d_in[0];
    const float* Wq = (const float*)d_in[1];
    const float* Wk = (const float*)d_in[2];
    const float* Wv = (const float*)d_in[3];
    const float* Wo = (const float*)d_in[4];
    const float* bo = (const float*)d_in[5];
    float* out = (float*)d_out;

    float* ws = (float*)d_ws;
    const size_t NELT = (size_t)MM * DD;     // 4M floats = 16 MB
    float* Qb  = ws;
    float* Kb  = ws + NELT;
    float* Vb  = ws + 2*NELT;
    float* Ctx = ws + 3*NELT;

    dim3 ggrid(DD/64, MM/64);
    dim3 gblk(256);
    hipLaunchKernelGGL((gemm_kernel<true,  false>), ggrid, gblk, 0, stream, x, Wq, nullptr, Qb);
    hipLaunchKernelGGL((gemm_kernel<true,  false>), ggrid, gblk, 0, stream, x, Wk, nullptr, Kb);
    hipLaunchKernelGGL((gemm_kernel<true,  false>), ggrid, gblk, 0, stream, x, Wv, nullptr, Vb);

    dim3 agrid(SS/64, HH, BB);
    hipLaunchKernelGGL(attn_kernel, agrid, gblk, 0, stream, Qb, Kb, Vb, Ctx);

    hipLaunchKernelGGL((gemm_kernel<false, true >), ggrid, gblk, 0, stream, Ctx, Wo, bo, out);
}

// Round 2
// 627.915 us; speedup vs baseline: 2.4026x; 2.4026x over previous
//
#include <hip/hip_runtime.h>
#include <math.h>

#define BB 2
#define SS 2048
#define DD 1024
#define HH 16
#define HD 64
#define MM (BB*SS)   // 4096

typedef float  f32x4 __attribute__((ext_vector_type(4)));
typedef short  s16x8 __attribute__((ext_vector_type(8)));
typedef unsigned short u16;
typedef u16    u16x4 __attribute__((ext_vector_type(4)));
typedef unsigned int u32;
typedef u32    u32x4 __attribute__((ext_vector_type(4)));

static __device__ __forceinline__ u16 f2bf(float f) {
    u32 u = __float_as_uint(f);
    u = (u + 0x7FFFu + ((u >> 16) & 1u)) >> 16;   // RNE
    return (u16)u;
}

// ---------------------------------------------------------------------------
// fp32 GEMM: C[M,D] = A[M,D] @ W[D,D] (+bias).
// MODE 0: fp32 out [M,D] (+bias).  MODE 1: bf16 out [B,H,S,HD], scaled.
// MODE 2: bf16 out transposed [B,H,HD,S] (for V^T) via LDS transpose.
// 64x64 tile, BK=16, 256 threads, 4x4 per thread.
// ---------------------------------------------------------------------------
template<int MODE, bool BIAS>
__global__ __launch_bounds__(256) void gemm_kernel(const float* __restrict__ A,
                                                   const float* __restrict__ W,
                                                   const float* __restrict__ bias,
                                                   void* __restrict__ Cout,
                                                   float scale) {
    __shared__ float As[16][68];   // [k][row]
    __shared__ float Ws[16][68];   // [k][col]
    const int t  = threadIdx.x;
    const int tx = t % 16;
    const int ty = t / 16;
    const int col0 = blockIdx.x * 64;
    const int row0 = blockIdx.y * 64;
    float acc[4][4] = {};
    for (int k0 = 0; k0 < DD; k0 += 16) {
        {
            int c = t % 16;
            int r = t / 16;
            #pragma unroll
            for (int rr = 0; rr < 4; ++rr)
                As[c][r + rr*16] = A[(size_t)(row0 + r + rr*16)*DD + k0 + c];
        }
        {
            int c = t % 64;
            int r = t / 64;
            #pragma unroll
            for (int rr = 0; rr < 4; ++rr)
                Ws[r + rr*4][c] = W[(size_t)(k0 + r + rr*4)*DD + col0 + c];
        }
        __syncthreads();
        #pragma unroll
        for (int kk = 0; kk < 16; ++kk) {
            float a[4], b[4];
            #pragma unroll
            for (int i = 0; i < 4; ++i) a[i] = As[kk][ty*4 + i];
            #pragma unroll
            for (int j = 0; j < 4; ++j) b[j] = Ws[kk][tx*4 + j];
            #pragma unroll
            for (int i = 0; i < 4; ++i)
                #pragma unroll
                for (int j = 0; j < 4; ++j)
                    acc[i][j] = fmaf(a[i], b[j], acc[i][j]);
        }
        __syncthreads();
    }

    if constexpr (MODE == 0) {
        float* out = (float*)Cout;
        #pragma unroll
        for (int i = 0; i < 4; ++i) {
            int r = row0 + ty*4 + i;
            #pragma unroll
            for (int j = 0; j < 4; ++j) {
                int c = col0 + tx*4 + j;
                float v = acc[i][j];
                if (BIAS) v += bias[c];
                out[(size_t)r*DD + c] = v;
            }
        }
    } else if constexpr (MODE == 1) {
        // bf16 [B,H,S,HD]; col0 is head-aligned (64-wide heads)
        u16* out = (u16*)Cout;
        const int h  = col0 / HD;
        #pragma unroll
        for (int i = 0; i < 4; ++i) {
            int r = row0 + ty*4 + i;
            int b_ = r / SS, s_ = r % SS;
            u16x4 pk;
            #pragma unroll
            for (int j = 0; j < 4; ++j) pk[j] = f2bf(acc[i][j] * scale);
            *(u16x4*)(out + (((size_t)b_*HH + h)*SS + s_)*HD + tx*4) = pk;
        }
    } else {
        // bf16 [B,H,HD,S] transposed write via LDS
        __shared__ u16 tr[64][80];
        #pragma unroll
        for (int i = 0; i < 4; ++i)
            #pragma unroll
            for (int j = 0; j < 4; ++j)
                tr[tx*4 + j][ty*4 + i] = f2bf(acc[i][j]);
        __syncthreads();
        u16* out = (u16*)Cout;
        const int h  = col0 / HD;
        const int b_ = row0 / SS;
        const int s0 = row0 % SS;
        int d  = t >> 2;
        int sc = (t & 3) * 16;
        const u16* trr = &tr[d][sc];
        u16* op = out + (((size_t)b_*HH + h)*HD + d)*SS + s0 + sc;
        *(u32x4*)op       = *(const u32x4*)trr;
        *(u32x4*)(op + 8) = *(const u32x4*)(trr + 8);
    }
}

// ---------------------------------------------------------------------------
// MFMA flash attention (causal, scores pre-scaled via Q*0.2).
// Block: 256 thr = 4 waves; wave w owns q rows qt*64 + w*16 .. +15.
// Per KV tile (64 keys): S^T = mfma(K, Q) (swapped, both operands row-reads),
// wave-parallel online softmax (4-lane-group shfl_xor), P -> swizzled LDS,
// PV = mfma(P, V^T-rows). K/V^T tiles staged in XOR-swizzled LDS.
// Q: bf16 [B,H,S,HD] (pre-scaled by 0.2). K: bf16 [B,H,S,HD]. Vt: bf16 [B,H,HD,S].
// ctx out: fp32 [B,S,D].
// ---------------------------------------------------------------------------
__global__ __launch_bounds__(256) void attn_mfma(const u16* __restrict__ Q,
                                                 const u16* __restrict__ K,
                                                 const u16* __restrict__ Vt,
                                                 float* __restrict__ ctx) {
    __shared__ u32x4 smem4[24576/16];
    char* smem = (char*)smem4;
    char* Ksm = smem;            // 8KB: 64 rows(key) x 128B, XOR-swizzled
    char* Vsm = smem + 8192;     // 8KB: 64 rows(dim) x 128B, XOR-swizzled
    const int qt = blockIdx.x;
    const int h  = blockIdx.y;
    const int b  = blockIdx.z;
    const int t  = threadIdx.x;
    const int w  = t >> 6;
    const int l  = t & 63;
    const int g  = l >> 4;
    const int q15 = l & 15;
    char* Psm = smem + 16384 + w*2048;  // per-wave 16 rows(q) x 128B

    const size_t bh = ((size_t)b*HH + h) * SS;
    const u16* Qw = Q + (bh + (size_t)qt*64 + w*16 + q15) * HD;
    s16x8 qf0 = *(const s16x8*)(Qw + g*8);
    s16x8 qf1 = *(const s16x8*)(Qw + 32 + g*8);

    f32x4 acc[4] = {};           // acc[n][r]: ctx[q = w*16+4g+r][dim = n*16+q15]
    float m = -1e30f, lsum = 0.f;
    const int qg = qt*64 + w*16 + q15;   // this lane's softmax q row (absolute)

    for (int kt = 0; kt <= qt; ++kt) {
        {   // stage K tile [64key][64d] and Vt tile [64d][64key] (swizzled)
            const u16* Kg = K  + (bh + (size_t)kt*64) * HD;
            const u16* Vg = Vt + ((size_t)(b*HH + h)) * HD * SS + (size_t)kt*64;
            #pragma unroll
            for (int u = 0; u < 2; ++u) {
                int c = t + u*256;          // 0..511
                int row = c >> 3;
                int cb  = (c & 7) * 16;
                int sw  = (row & 7) << 4;
                u32x4 kv = *(const u32x4*)(Kg + (size_t)row*HD + (c&7)*8);
                *(u32x4*)(Ksm + row*128 + (cb ^ sw)) = kv;
                u32x4 vv = *(const u32x4*)(Vg + (size_t)row*SS + (c&7)*8);
                *(u32x4*)(Vsm + row*128 + (cb ^ sw)) = vv;
            }
        }
        __syncthreads();

        // ---- S^T[key][q] = K . Q^T : 4 key-blocks x 2 k-frags
        f32x4 st[4];
        #pragma unroll
        for (int kb = 0; kb < 4; ++kb) {
            f32x4 z = {0.f, 0.f, 0.f, 0.f};
            int row = kb*16 + q15;
            int sw  = (row & 7) << 4;
            s16x8 a0 = *(const s16x8*)(Ksm + row*128 + ((g*16)      ^ sw));
            s16x8 a1 = *(const s16x8*)(Ksm + row*128 + ((64 + g*16) ^ sw));
            z = __builtin_amdgcn_mfma_f32_16x16x32_bf16(a0, qf0, z, 0, 0, 0);
            z = __builtin_amdgcn_mfma_f32_16x16x32_bf16(a1, qf1, z, 0, 0, 0);
            st[kb] = z;   // st[kb][r] = S[q=q15][key = kt*64 + kb*16 + 4g + r]
        }

        // ---- causal mask (only block-diagonal tile needs it)
        if (kt == qt) {
            #pragma unroll
            for (int kb = 0; kb < 4; ++kb)
                #pragma unroll
                for (int r = 0; r < 4; ++r) {
                    int key = kt*64 + kb*16 + g*4 + r;
                    if (key > qg) st[kb][r] = -1e30f;
                }
        }

        // ---- online softmax (per q = q15; partner lanes at xor 16,32)
        float tmax = -1e30f;
        #pragma unroll
        for (int kb = 0; kb < 4; ++kb)
            #pragma unroll
            for (int r = 0; r < 4; ++r) tmax = fmaxf(tmax, st[kb][r]);
        tmax = fmaxf(tmax, __shfl_xor(tmax, 16));
        tmax = fmaxf(tmax, __shfl_xor(tmax, 32));
        float mnew = fmaxf(m, tmax);
        float scl  = __expf(m - mnew);
        float ps = 0.f;
        #pragma unroll
        for (int kb = 0; kb < 4; ++kb)
            #pragma unroll
            for (int r = 0; r < 4; ++r) {
                float p = __expf(st[kb][r] - mnew);
                st[kb][r] = p;
                ps += p;
            }
        ps += __shfl_xor(ps, 16);
        ps += __shfl_xor(ps, 32);
        lsum = lsum * scl + ps;
        m = mnew;

        // ---- rescale acc (acc q-row = 4g+r; scl lives on lane with q15 = 4g+r)
        #pragma unroll
        for (int r = 0; r < 4; ++r) {
            float sr = __shfl(scl, g*4 + r);
            #pragma unroll
            for (int n = 0; n < 4; ++n) acc[n][r] *= sr;
        }

        // ---- P -> LDS (bf16, per-wave, swizzled rows)
        {
            int swp = (q15 & 7) << 4;
            #pragma unroll
            for (int kb = 0; kb < 4; ++kb) {
                u16x4 pk;
                pk[0] = f2bf(st[kb][0]); pk[1] = f2bf(st[kb][1]);
                pk[2] = f2bf(st[kb][2]); pk[3] = f2bf(st[kb][3]);
                *(u16x4*)(Psm + q15*128 + ((kb*32 + g*8) ^ swp)) = pk;
            }
            // ---- PV: ctx += P @ V  (A = P[16q][32k], B = V[32k][16d] from Vt rows)
            s16x8 pa0 = *(const s16x8*)(Psm + q15*128 + ((g*16)      ^ swp));
            s16x8 pa1 = *(const s16x8*)(Psm + q15*128 + ((64 + g*16) ^ swp));
            #pragma unroll
            for (int n = 0; n < 4; ++n) {
                int row = n*16 + q15;
                int sw  = (row & 7) << 4;
                s16x8 v0 = *(const s16x8*)(Vsm + row*128 + ((g*16)      ^ sw));
                s16x8 v1 = *(const s16x8*)(Vsm + row*128 + ((64 + g*16) ^ sw));
                acc[n] = __builtin_amdgcn_mfma_f32_16x16x32_bf16(pa0, v0, acc[n], 0, 0, 0);
                acc[n] = __builtin_amdgcn_mfma_f32_16x16x32_bf16(pa1, v1, acc[n], 0, 0, 0);
            }
        }
        __syncthreads();
    }

    // ---- epilogue: normalize and write ctx fp32 [B,S,D]
    #pragma unroll
    for (int r = 0; r < 4; ++r) {
        float inv = 1.f / __shfl(lsum, g*4 + r);
        int qrow = qt*64 + w*16 + g*4 + r;
        float* crow = ctx + ((size_t)b*SS + qrow)*DD + h*HD;
        #pragma unroll
        for (int n = 0; n < 4; ++n)
            crow[n*16 + q15] = acc[n][r] * inv;
    }
}

extern "C" void kernel_launch(void* const* d_in, const int* in_sizes, int n_in,
                              void* d_out, int out_size, void* d_ws, size_t ws_size,
                              hipStream_t stream) {
    const float* x  = (const float*)d_in[0];
    const float* Wq = (const float*)d_in[1];
    const float* Wk = (const float*)d_in[2];
    const float* Wv = (const float*)d_in[3];
    const float* Wo = (const float*)d_in[4];
    const float* bo = (const float*)d_in[5];
    float* out = (float*)d_out;

    const size_t NELT = (size_t)MM * DD;     // 4M elements
    u16* wsb = (u16*)d_ws;
    u16*  Qb  = wsb;                 // 8MB bf16 [B,H,S,HD] (prescaled 0.2)
    u16*  Kb  = wsb + NELT;          // 8MB bf16 [B,H,S,HD]
    u16*  Vtb = wsb + 2*NELT;        // 8MB bf16 [B,H,HD,S]
    float* Ctx = (float*)(wsb + 3*NELT);  // 16MB fp32 [B,S,D]

    dim3 ggrid(DD/64, MM/64);
    dim3 gblk(256);
    hipLaunchKernelGGL((gemm_kernel<1, false>), ggrid, gblk, 0, stream, x, Wq, nullptr, (void*)Qb, 0.2f);
    hipLaunchKernelGGL((gemm_kernel<1, false>), ggrid, gblk, 0, stream, x, Wk, nullptr, (void*)Kb, 1.0f);
    hipLaunchKernelGGL((gemm_kernel<2, false>), ggrid, gblk, 0, stream, x, Wv, nullptr, (void*)Vtb, 1.0f);

    dim3 agrid(SS/64, HH, BB);
    hipLaunchKernelGGL(attn_mfma, agrid, gblk, 0, stream, Qb, Kb, Vtb, Ctx);

    hipLaunchKernelGGL((gemm_kernel<0, true>), ggrid, gblk, 0, stream, Ctx, Wo, bo, (void*)out, 1.0f);
}

// Round 5
// 196.950 us; speedup vs baseline: 7.6601x; 3.1882x over previous
//
#include <hip/hip_runtime.h>
#include <math.h>

#define BB 2
#define SS 2048
#define DD 1024
#define HH 16
#define HD 64
#define MM (BB*SS)   // 4096

typedef float  f32x4 __attribute__((ext_vector_type(4)));
typedef short  s16x8 __attribute__((ext_vector_type(8)));
typedef unsigned short u16;
typedef u16    u16x4 __attribute__((ext_vector_type(4)));
typedef unsigned int u32;
typedef u32    u32x4 __attribute__((ext_vector_type(4)));

static __device__ __forceinline__ u16 f2bf(float f) {
    u32 u = __float_as_uint(f);
    u = (u + 0x7FFFu + ((u >> 16) & 1u)) >> 16;   // RNE
    return (u16)u;
}

// ---------------------------------------------------------------------------
// x fp32 [4096][1024] -> bf16 (row-major unchanged)
// ---------------------------------------------------------------------------
__global__ __launch_bounds__(256) void conv_x(const float* __restrict__ in,
                                              u16* __restrict__ outb) {
    int i = blockIdx.x * 256 + threadIdx.x;      // each handles 8 elements
    const f32x4* p = (const f32x4*)in;
    f32x4 a = p[i*2], b = p[i*2 + 1];
    u16x4 lo, hi;
    lo[0]=f2bf(a.x); lo[1]=f2bf(a.y); lo[2]=f2bf(a.z); lo[3]=f2bf(a.w);
    hi[0]=f2bf(b.x); hi[1]=f2bf(b.y); hi[2]=f2bf(b.z); hi[3]=f2bf(b.w);
    *(u16x4*)(outb + (size_t)i*8)     = lo;
    *(u16x4*)(outb + (size_t)i*8 + 4) = hi;
}

// ---------------------------------------------------------------------------
// W fp32 [K=1024][N=1024] -> W^T bf16 [N][K].  z selects one of 4 weights.
// Load: 4 passes (4096 f32 / 4-per-thread). Writeback: ONE pass
// (256 threads x 16 u16 = 4096 = 64x64 tile). (Round-4 bug: 4-pass writeback
// ran c=idx>>2 up to 255 -> OOB LDS reads + cross-tile garbage writes.)
// ---------------------------------------------------------------------------
__global__ __launch_bounds__(256) void conv_wt(const float* __restrict__ W0,
                                               const float* __restrict__ W1,
                                               const float* __restrict__ W2,
                                               const float* __restrict__ W3,
                                               u16* __restrict__ WT) {
    const int z = blockIdx.z;
    const float* W = (z==0) ? W0 : (z==1) ? W1 : (z==2) ? W2 : W3;
    u16* dst = WT + (size_t)z * 1024 * 1024;
    __shared__ u16 tr[64][72];
    const int t = threadIdx.x;
    const int r0 = blockIdx.y * 64, c0 = blockIdx.x * 64;
    #pragma unroll
    for (int u = 0; u < 4; ++u) {
        int idx = u*256 + t;
        int r = idx >> 4, c4 = (idx & 15) * 4;
        f32x4 v = *(const f32x4*)(W + (size_t)(r0 + r)*1024 + c0 + c4);
        tr[c4+0][r] = f2bf(v.x);
        tr[c4+1][r] = f2bf(v.y);
        tr[c4+2][r] = f2bf(v.z);
        tr[c4+3][r] = f2bf(v.w);
    }
    __syncthreads();
    {
        int c = t >> 2, rq = (t & 3) * 16;       // c: 0..63, rq: 0,16,32,48
        u32x4 v0 = *(const u32x4*)&tr[c][rq];
        u32x4 v1 = *(const u32x4*)&tr[c][rq + 8];
        u16* op = dst + (size_t)(c0 + c)*1024 + r0 + rq;
        *(u32x4*)op       = v0;
        *(u32x4*)(op + 8) = v1;
    }
}

// ---------------------------------------------------------------------------
// bf16 MFMA GEMM: C[M,N] = A[M,1024] @ WT[N,1024]^T.  BM=128, BK=64, BN=NJ*32.
// 256 thr = 4 waves (2x2), wave tile 64 x NJ*16, 16x16x32 MFMA.
// Staging: global -> regs (u32x4) -> XOR-swizzled ds_write (attn-proven path).
// EPI 0: QKV epilogue -> Qb(bf16,*0.2,[B,H,S,HD]), Kb(same), Vt(bf16,[B,H,HD,S])
// EPI 1: fp32 out [M][1024] + bias
// ---------------------------------------------------------------------------
template<int EPI, int NJ>
__global__ __launch_bounds__(256) void mfma_gemm(const u16* __restrict__ A,
                                                 const u16* __restrict__ WT,
                                                 const float* __restrict__ bias,
                                                 u16* __restrict__ Qb,
                                                 u16* __restrict__ Kb,
                                                 u16* __restrict__ Vtb,
                                                 float* __restrict__ outF) {
    constexpr int BN = NJ * 32;
    __shared__ u32x4 smemv[2048];                 // 32 KB
    char* smem = (char*)smemv;
    char* Bsm  = smem + 16384;
    const int t   = threadIdx.x;
    const int w   = t >> 6;
    const int l   = t & 63;
    const int c15 = l & 15;
    const int g16 = ((l >> 4) & 3) << 4;          // byte offset of k-group
    const int mw  = w >> 1, nw = w & 1;
    const int brow = blockIdx.y * 128;
    const int bcol = blockIdx.x * BN;

    f32x4 acc[4][NJ] = {};

    const u16* Asrc = A  + (size_t)brow * DD;
    const u16* Bsrc = WT + (size_t)bcol * DD;

    for (int k0 = 0; k0 < DD; k0 += 64) {
        u32x4 av[4], bv[NJ];
        #pragma unroll
        for (int u = 0; u < 4; ++u) {             // A tile: 128 rows x 64 k
            int idx = u*256 + t;
            int row = idx >> 3;
            int ce  = (idx & 7) << 3;             // element offset in row
            av[u] = *(const u32x4*)(Asrc + (size_t)row*DD + k0 + ce);
        }
        #pragma unroll
        for (int u = 0; u < NJ; ++u) {            // B tile: BN rows x 64 k
            int idx = u*256 + t;
            int row = idx >> 3;
            int ce  = (idx & 7) << 3;
            bv[u] = *(const u32x4*)(Bsrc + (size_t)row*DD + k0 + ce);
        }
        #pragma unroll
        for (int u = 0; u < 4; ++u) {
            int idx = u*256 + t;
            int row = idx >> 3;
            int cb  = (idx & 7) << 4;             // byte offset in 128B row
            *(u32x4*)(smem + row*128 + (cb ^ ((row & 7) << 4))) = av[u];
        }
        #pragma unroll
        for (int u = 0; u < NJ; ++u) {
            int idx = u*256 + t;
            int row = idx >> 3;
            int cb  = (idx & 7) << 4;
            *(u32x4*)(Bsm + row*128 + (cb ^ ((row & 7) << 4))) = bv[u];
        }
        __syncthreads();

        s16x8 af[4][2], bf[NJ][2];
        #pragma unroll
        for (int mi = 0; mi < 4; ++mi) {
            int row = mw*64 + mi*16 + c15;
            int sw  = (row & 7) << 4;
            af[mi][0] = *(const s16x8*)(smem + row*128 + ((g16)      ^ sw));
            af[mi][1] = *(const s16x8*)(smem + row*128 + ((64 + g16) ^ sw));
        }
        #pragma unroll
        for (int nj = 0; nj < NJ; ++nj) {
            int row = nw*(NJ*16) + nj*16 + c15;
            int sw  = (row & 7) << 4;
            bf[nj][0] = *(const s16x8*)(Bsm + row*128 + ((g16)      ^ sw));
            bf[nj][1] = *(const s16x8*)(Bsm + row*128 + ((64 + g16) ^ sw));
        }
        #pragma unroll
        for (int c = 0; c < 2; ++c)
            #pragma unroll
            for (int mi = 0; mi < 4; ++mi)
                #pragma unroll
                for (int nj = 0; nj < NJ; ++nj)
                    acc[mi][nj] = __builtin_amdgcn_mfma_f32_16x16x32_bf16(
                        af[mi][c], bf[nj][c], acc[mi][nj], 0, 0, 0);
        __syncthreads();
    }

    if constexpr (EPI == 1) {
        #pragma unroll
        for (int mi = 0; mi < 4; ++mi)
            #pragma unroll
            for (int r = 0; r < 4; ++r) {
                int mg = brow + mw*64 + mi*16 + ((l >> 4) & 3)*4 + r;
                #pragma unroll
                for (int nj = 0; nj < NJ; ++nj) {
                    int nc = bcol + nw*(NJ*16) + nj*16 + c15;
                    outF[(size_t)mg*DD + nc] = acc[mi][nj][r] + bias[nc];
                }
            }
    } else {
        const int wq   = blockIdx.x >> 3;                  // 0=Q, 1=K, 2=V
        const int ncw0 = (blockIdx.x & 7)*128 + nw*64;     // within-weight col base
        if (wq < 2) {
            u16* dst  = wq ? Kb : Qb;
            float scl = wq ? 1.0f : 0.2f;
            #pragma unroll
            for (int mi = 0; mi < 4; ++mi)
                #pragma unroll
                for (int r = 0; r < 4; ++r) {
                    int mg = brow + mw*64 + mi*16 + ((l >> 4) & 3)*4 + r;
                    int b_ = mg >> 11, s_ = mg & (SS-1);
                    #pragma unroll
                    for (int nj = 0; nj < NJ; ++nj) {
                        int nc = ncw0 + nj*16 + c15;
                        int h_ = nc >> 6, d_ = nc & 63;
                        dst[(((size_t)b_*HH + h_)*SS + s_)*HD + d_] =
                            f2bf(acc[mi][nj][r] * scl);
                    }
                }
        } else {
            // V: transpose 64x64 per wave via LDS -> Vt [B,H,HD,S]
            char* tw = smem + w*8192;
            #pragma unroll
            for (int nj = 0; nj < NJ; ++nj)
                #pragma unroll
                for (int mi = 0; mi < 4; ++mi)
                    #pragma unroll
                    for (int r = 0; r < 4; ++r) {
                        int n = nj*16 + c15;
                        int m = mi*16 + ((l >> 4) & 3)*4 + r;
                        *(u16*)(tw + n*128 + ((m*2) ^ ((n & 7) << 4))) =
                            f2bf(acc[mi][nj][r]);
                    }
            __syncthreads();
            #pragma unroll
            for (int it = 0; it < 8; ++it) {
                int n  = it*8 + (l >> 3);
                int mb = l & 7;
                u32x4 v = *(const u32x4*)(tw + n*128 + ((mb*16) ^ ((n & 7) << 4)));
                int nc = ncw0 + n;
                int h_ = nc >> 6, d_ = nc & 63;
                int mg0 = brow + mw*64;
                int b_ = mg0 >> 11;
                int sb = (mg0 & (SS-1)) + mb*8;
                *(u32x4*)(Vtb + (((size_t)b_*HH + h_)*HD + d_)*SS + sb) = v;
            }
        }
    }
}

// ---------------------------------------------------------------------------
// MFMA flash attention (causal; Q pre-scaled by 0.2 in QKV epilogue).
// Block: 4 waves; wave w owns q rows qt*64 + w*16 .. +15. ctx out bf16 [B,S,D].
// ---------------------------------------------------------------------------
__global__ __launch_bounds__(256) void attn_mfma(const u16* __restrict__ Q,
                                                 const u16* __restrict__ K,
                                                 const u16* __restrict__ Vt,
                                                 u16* __restrict__ ctx) {
    __shared__ u32x4 smem4[24576/16];
    char* smem = (char*)smem4;
    char* Ksm = smem;            // 8KB: 64 rows(key) x 128B, XOR-swizzled
    char* Vsm = smem + 8192;     // 8KB: 64 rows(dim) x 128B, XOR-swizzled
    const int qt = blockIdx.x;
    const int h  = blockIdx.y;
    const int b  = blockIdx.z;
    const int t  = threadIdx.x;
    const int w  = t >> 6;
    const int l  = t & 63;
    const int g  = l >> 4;
    const int q15 = l & 15;
    char* Psm = smem + 16384 + w*2048;  // per-wave 16 rows(q) x 128B

    const size_t bh = ((size_t)b*HH + h) * SS;
    const u16* Qw = Q + (bh + (size_t)qt*64 + w*16 + q15) * HD;
    s16x8 qf0 = *(const s16x8*)(Qw + g*8);
    s16x8 qf1 = *(const s16x8*)(Qw + 32 + g*8);

    f32x4 acc[4] = {};           // acc[n][r]: ctx[q = w*16+4g+r][dim = n*16+q15]
    float m = -1e30f, lsum = 0.f;
    const int qg = qt*64 + w*16 + q15;

    for (int kt = 0; kt <= qt; ++kt) {
        {
            const u16* Kg = K  + (bh + (size_t)kt*64) * HD;
            const u16* Vg = Vt + ((size_t)(b*HH + h)) * HD * SS + (size_t)kt*64;
            #pragma unroll
            for (int u = 0; u < 2; ++u) {
                int c = t + u*256;
                int row = c >> 3;
                int cb  = (c & 7) * 16;
                int sw  = (row & 7) << 4;
                u32x4 kv = *(const u32x4*)(Kg + (size_t)row*HD + (c&7)*8);
                *(u32x4*)(Ksm + row*128 + (cb ^ sw)) = kv;
                u32x4 vv = *(const u32x4*)(Vg + (size_t)row*SS + (c&7)*8);
                *(u32x4*)(Vsm + row*128 + (cb ^ sw)) = vv;
            }
        }
        __syncthreads();

        f32x4 st[4];
        #pragma unroll
        for (int kb = 0; kb < 4; ++kb) {
            f32x4 z = {0.f, 0.f, 0.f, 0.f};
            int row = kb*16 + q15;
            int sw  = (row & 7) << 4;
            s16x8 a0 = *(const s16x8*)(Ksm + row*128 + ((g*16)      ^ sw));
            s16x8 a1 = *(const s16x8*)(Ksm + row*128 + ((64 + g*16) ^ sw));
            z = __builtin_amdgcn_mfma_f32_16x16x32_bf16(a0, qf0, z, 0, 0, 0);
            z = __builtin_amdgcn_mfma_f32_16x16x32_bf16(a1, qf1, z, 0, 0, 0);
            st[kb] = z;
        }

        if (kt == qt) {
            #pragma unroll
            for (int kb = 0; kb < 4; ++kb)
                #pragma unroll
                for (int r = 0; r < 4; ++r) {
                    int key = kt*64 + kb*16 + g*4 + r;
                    if (key > qg) st[kb][r] = -1e30f;
                }
        }

        float tmax = -1e30f;
        #pragma unroll
        for (int kb = 0; kb < 4; ++kb)
            #pragma unroll
            for (int r = 0; r < 4; ++r) tmax = fmaxf(tmax, st[kb][r]);
        tmax = fmaxf(tmax, __shfl_xor(tmax, 16));
        tmax = fmaxf(tmax, __shfl_xor(tmax, 32));
        float mnew = fmaxf(m, tmax);
        float scl  = __expf(m - mnew);
        float ps = 0.f;
        #pragma unroll
        for (int kb = 0; kb < 4; ++kb)
            #pragma unroll
            for (int r = 0; r < 4; ++r) {
                float p = __expf(st[kb][r] - mnew);
                st[kb][r] = p;
                ps += p;
            }
        ps += __shfl_xor(ps, 16);
        ps += __shfl_xor(ps, 32);
        lsum = lsum * scl + ps;
        m = mnew;

        #pragma unroll
        for (int r = 0; r < 4; ++r) {
            float sr = __shfl(scl, g*4 + r);
            #pragma unroll
            for (int n = 0; n < 4; ++n) acc[n][r] *= sr;
        }

        {
            int swp = (q15 & 7) << 4;
            #pragma unroll
            for (int kb = 0; kb < 4; ++kb) {
                u16x4 pk;
                pk[0] = f2bf(st[kb][0]); pk[1] = f2bf(st[kb][1]);
                pk[2] = f2bf(st[kb][2]); pk[3] = f2bf(st[kb][3]);
                *(u16x4*)(Psm + q15*128 + ((kb*32 + g*8) ^ swp)) = pk;
            }
            s16x8 pa0 = *(const s16x8*)(Psm + q15*128 + ((g*16)      ^ swp));
            s16x8 pa1 = *(const s16x8*)(Psm + q15*128 + ((64 + g*16) ^ swp));
            #pragma unroll
            for (int n = 0; n < 4; ++n) {
                int row = n*16 + q15;
                int sw  = (row & 7) << 4;
                s16x8 v0 = *(const s16x8*)(Vsm + row*128 + ((g*16)      ^ sw));
                s16x8 v1 = *(const s16x8*)(Vsm + row*128 + ((64 + g*16) ^ sw));
                acc[n] = __builtin_amdgcn_mfma_f32_16x16x32_bf16(pa0, v0, acc[n], 0, 0, 0);
                acc[n] = __builtin_amdgcn_mfma_f32_16x16x32_bf16(pa1, v1, acc[n], 0, 0, 0);
            }
        }
        __syncthreads();
    }

    #pragma unroll
    for (int r = 0; r < 4; ++r) {
        float inv = 1.f / __shfl(lsum, g*4 + r);
        int qrow = qt*64 + w*16 + g*4 + r;
        u16* crow = ctx + ((size_t)b*SS + qrow)*DD + h*HD;
        #pragma unroll
        for (int n = 0; n < 4; ++n)
            crow[n*16 + q15] = f2bf(acc[n][r] * inv);
    }
}

extern "C" void kernel_launch(void* const* d_in, const int* in_sizes, int n_in,
                              void* d_out, int out_size, void* d_ws, size_t ws_size,
                              hipStream_t stream) {
    const float* x  = (const float*)d_in[0];
    const float* Wq = (const float*)d_in[1];
    const float* Wk = (const float*)d_in[2];
    const float* Wv = (const float*)d_in[3];
    const float* Wo = (const float*)d_in[4];
    const float* bo = (const float*)d_in[5];
    float* out = (float*)d_out;

    const size_t NELT = (size_t)MM * DD;          // 4M
    const size_t NW   = (size_t)1024 * 1024;      // 1M per weight
    u16* wsb  = (u16*)d_ws;
    u16* xb   = wsb;                    // 4M  bf16 x
    u16* WT   = wsb + NELT;             // 4x1M bf16 W^T (q,k,v,o)
    u16* Qb   = wsb + NELT + 4*NW;      // 4M
    u16* Kb   = Qb + NELT;              // 4M
    u16* Vtb  = Kb + NELT;              // 4M
    u16* Ctxb = Vtb + NELT;             // 4M
    u16* WTqkv = WT;
    u16* WTo   = WT + 3*NW;

    hipLaunchKernelGGL(conv_x, dim3(2048), dim3(256), 0, stream, x, xb);
    hipLaunchKernelGGL(conv_wt, dim3(16,16,4), dim3(256), 0, stream, Wq, Wk, Wv, Wo, WT);

    hipLaunchKernelGGL((mfma_gemm<0,4>), dim3(24,32), dim3(256), 0, stream,
                       xb, WTqkv, nullptr, Qb, Kb, Vtb, nullptr);

    hipLaunchKernelGGL(attn_mfma, dim3(32,16,2), dim3(256), 0, stream, Qb, Kb, Vtb, Ctxb);

    hipLaunchKernelGGL((mfma_gemm<1,2>), dim3(16,32), dim3(256), 0, stream,
                       Ctxb, WTo, bo, nullptr, nullptr, nullptr, out);
}

// Round 6
// 158.969 us; speedup vs baseline: 9.4902x; 1.2389x over previous
//
#include <hip/hip_runtime.h>
#include <math.h>

#define BB 2
#define SS 2048
#define DD 1024
#define HH 16
#define HD 64
#define MM (BB*SS)   // 4096

typedef float  f32x4 __attribute__((ext_vector_type(4)));
typedef short  s16x8 __attribute__((ext_vector_type(8)));
typedef unsigned short u16;
typedef u16    u16x4 __attribute__((ext_vector_type(4)));
typedef unsigned int u32;
typedef u32    u32x4 __attribute__((ext_vector_type(4)));

static __device__ __forceinline__ u16 f2bf(float f) {
    u32 u = __float_as_uint(f);
    u = (u + 0x7FFFu + ((u >> 16) & 1u)) >> 16;   // RNE
    return (u16)u;
}

// ---------------------------------------------------------------------------
// x fp32 [4096][1024] -> bf16 (row-major unchanged)
// ---------------------------------------------------------------------------
__global__ __launch_bounds__(256) void conv_x(const float* __restrict__ in,
                                              u16* __restrict__ outb) {
    int i = blockIdx.x * 256 + threadIdx.x;      // each handles 8 elements
    const f32x4* p = (const f32x4*)in;
    f32x4 a = p[i*2], b = p[i*2 + 1];
    u16x4 lo, hi;
    lo[0]=f2bf(a.x); lo[1]=f2bf(a.y); lo[2]=f2bf(a.z); lo[3]=f2bf(a.w);
    hi[0]=f2bf(b.x); hi[1]=f2bf(b.y); hi[2]=f2bf(b.z); hi[3]=f2bf(b.w);
    *(u16x4*)(outb + (size_t)i*8)     = lo;
    *(u16x4*)(outb + (size_t)i*8 + 4) = hi;
}

// ---------------------------------------------------------------------------
// W fp32 [K=1024][N=1024] -> W^T bf16 [N][K].  z selects one of 4 weights.
// Load: 4 passes. Writeback: ONE pass (256 thr x 16 u16 = 64x64 tile).
// ---------------------------------------------------------------------------
__global__ __launch_bounds__(256) void conv_wt(const float* __restrict__ W0,
                                               const float* __restrict__ W1,
                                               const float* __restrict__ W2,
                                               const float* __restrict__ W3,
                                               u16* __restrict__ WT) {
    const int z = blockIdx.z;
    const float* W = (z==0) ? W0 : (z==1) ? W1 : (z==2) ? W2 : W3;
    u16* dst = WT + (size_t)z * 1024 * 1024;
    __shared__ u16 tr[64][72];
    const int t = threadIdx.x;
    const int r0 = blockIdx.y * 64, c0 = blockIdx.x * 64;
    #pragma unroll
    for (int u = 0; u < 4; ++u) {
        int idx = u*256 + t;
        int r = idx >> 4, c4 = (idx & 15) * 4;
        f32x4 v = *(const f32x4*)(W + (size_t)(r0 + r)*1024 + c0 + c4);
        tr[c4+0][r] = f2bf(v.x);
        tr[c4+1][r] = f2bf(v.y);
        tr[c4+2][r] = f2bf(v.z);
        tr[c4+3][r] = f2bf(v.w);
    }
    __syncthreads();
    {
        int c = t >> 2, rq = (t & 3) * 16;       // c: 0..63, rq: 0,16,32,48
        u32x4 v0 = *(const u32x4*)&tr[c][rq];
        u32x4 v1 = *(const u32x4*)&tr[c][rq + 8];
        u16* op = dst + (size_t)(c0 + c)*1024 + r0 + rq;
        *(u32x4*)op       = v0;
        *(u32x4*)(op + 8) = v1;
    }
}

// ---------------------------------------------------------------------------
// bf16 MFMA GEMM: C[M,N] = A[M,1024] @ WT[N,1024]^T.  BM=128, BK=64, BN=NJ*32.
// 256 thr = 4 waves (2x2), wave tile 64 x NJ*16, 16x16x32 MFMA.
// Staging: global -> regs (u32x4) -> XOR-swizzled ds_write.
// EPI 0: QKV epilogue -> Qb(bf16,*0.2,[B,H,S,HD]), Kb(same), Vt(bf16,[B,H,HD,S])
// EPI 1: fp32 out [M][1024] + bias
// ---------------------------------------------------------------------------
template<int EPI, int NJ>
__global__ __launch_bounds__(256) void mfma_gemm(const u16* __restrict__ A,
                                                 const u16* __restrict__ WT,
                                                 const float* __restrict__ bias,
                                                 u16* __restrict__ Qb,
                                                 u16* __restrict__ Kb,
                                                 u16* __restrict__ Vtb,
                                                 float* __restrict__ outF) {
    constexpr int BN = NJ * 32;
    __shared__ u32x4 smemv[2048];                 // 32 KB
    char* smem = (char*)smemv;
    char* Bsm  = smem + 16384;
    const int t   = threadIdx.x;
    const int w   = t >> 6;
    const int l   = t & 63;
    const int c15 = l & 15;
    const int g16 = ((l >> 4) & 3) << 4;          // byte offset of k-group
    const int mw  = w >> 1, nw = w & 1;
    const int brow = blockIdx.y * 128;
    const int bcol = blockIdx.x * BN;

    f32x4 acc[4][NJ] = {};

    const u16* Asrc = A  + (size_t)brow * DD;
    const u16* Bsrc = WT + (size_t)bcol * DD;

    for (int k0 = 0; k0 < DD; k0 += 64) {
        u32x4 av[4], bv[NJ];
        #pragma unroll
        for (int u = 0; u < 4; ++u) {             // A tile: 128 rows x 64 k
            int idx = u*256 + t;
            int row = idx >> 3;
            int ce  = (idx & 7) << 3;             // element offset in row
            av[u] = *(const u32x4*)(Asrc + (size_t)row*DD + k0 + ce);
        }
        #pragma unroll
        for (int u = 0; u < NJ; ++u) {            // B tile: BN rows x 64 k
            int idx = u*256 + t;
            int row = idx >> 3;
            int ce  = (idx & 7) << 3;
            bv[u] = *(const u32x4*)(Bsrc + (size_t)row*DD + k0 + ce);
        }
        #pragma unroll
        for (int u = 0; u < 4; ++u) {
            int idx = u*256 + t;
            int row = idx >> 3;
            int cb  = (idx & 7) << 4;             // byte offset in 128B row
            *(u32x4*)(smem + row*128 + (cb ^ ((row & 7) << 4))) = av[u];
        }
        #pragma unroll
        for (int u = 0; u < NJ; ++u) {
            int idx = u*256 + t;
            int row = idx >> 3;
            int cb  = (idx & 7) << 4;
            *(u32x4*)(Bsm + row*128 + (cb ^ ((row & 7) << 4))) = bv[u];
        }
        __syncthreads();

        s16x8 af[4][2], bf[NJ][2];
        #pragma unroll
        for (int mi = 0; mi < 4; ++mi) {
            int row = mw*64 + mi*16 + c15;
            int sw  = (row & 7) << 4;
            af[mi][0] = *(const s16x8*)(smem + row*128 + ((g16)      ^ sw));
            af[mi][1] = *(const s16x8*)(smem + row*128 + ((64 + g16) ^ sw));
        }
        #pragma unroll
        for (int nj = 0; nj < NJ; ++nj) {
            int row = nw*(NJ*16) + nj*16 + c15;
            int sw  = (row & 7) << 4;
            bf[nj][0] = *(const s16x8*)(Bsm + row*128 + ((g16)      ^ sw));
            bf[nj][1] = *(const s16x8*)(Bsm + row*128 + ((64 + g16) ^ sw));
        }
        #pragma unroll
        for (int c = 0; c < 2; ++c)
            #pragma unroll
            for (int mi = 0; mi < 4; ++mi)
                #pragma unroll
                for (int nj = 0; nj < NJ; ++nj)
                    acc[mi][nj] = __builtin_amdgcn_mfma_f32_16x16x32_bf16(
                        af[mi][c], bf[nj][c], acc[mi][nj], 0, 0, 0);
        __syncthreads();
    }

    if constexpr (EPI == 1) {
        #pragma unroll
        for (int mi = 0; mi < 4; ++mi)
            #pragma unroll
            for (int r = 0; r < 4; ++r) {
                int mg = brow + mw*64 + mi*16 + ((l >> 4) & 3)*4 + r;
                #pragma unroll
                for (int nj = 0; nj < NJ; ++nj) {
                    int nc = bcol + nw*(NJ*16) + nj*16 + c15;
                    outF[(size_t)mg*DD + nc] = acc[mi][nj][r] + bias[nc];
                }
            }
    } else {
        const int wq   = blockIdx.x >> 3;                  // 0=Q, 1=K, 2=V
        const int ncw0 = (blockIdx.x & 7)*128 + nw*64;     // within-weight col base
        if (wq < 2) {
            u16* dst  = wq ? Kb : Qb;
            float scl = wq ? 1.0f : 0.2f;
            #pragma unroll
            for (int mi = 0; mi < 4; ++mi)
                #pragma unroll
                for (int r = 0; r < 4; ++r) {
                    int mg = brow + mw*64 + mi*16 + ((l >> 4) & 3)*4 + r;
                    int b_ = mg >> 11, s_ = mg & (SS-1);
                    #pragma unroll
                    for (int nj = 0; nj < NJ; ++nj) {
                        int nc = ncw0 + nj*16 + c15;
                        int h_ = nc >> 6, d_ = nc & 63;
                        dst[(((size_t)b_*HH + h_)*SS + s_)*HD + d_] =
                            f2bf(acc[mi][nj][r] * scl);
                    }
                }
        } else {
            // V: transpose 64x64 per wave via LDS -> Vt [B,H,HD,S]
            char* tw = smem + w*8192;
            #pragma unroll
            for (int nj = 0; nj < NJ; ++nj)
                #pragma unroll
                for (int mi = 0; mi < 4; ++mi)
                    #pragma unroll
                    for (int r = 0; r < 4; ++r) {
                        int n = nj*16 + c15;
                        int m = mi*16 + ((l >> 4) & 3)*4 + r;
                        *(u16*)(tw + n*128 + ((m*2) ^ ((n & 7) << 4))) =
                            f2bf(acc[mi][nj][r]);
                    }
            __syncthreads();
            #pragma unroll
            for (int it = 0; it < 8; ++it) {
                int n  = it*8 + (l >> 3);
                int mb = l & 7;
                u32x4 v = *(const u32x4*)(tw + n*128 + ((mb*16) ^ ((n & 7) << 4)));
                int nc = ncw0 + n;
                int h_ = nc >> 6, d_ = nc & 63;
                int mg0 = brow + mw*64;
                int b_ = mg0 >> 11;
                int sb = (mg0 & (SS-1)) + mb*8;
                *(u32x4*)(Vtb + (((size_t)b_*HH + h_)*HD + d_)*SS + sb) = v;
            }
        }
    }
}

// ---------------------------------------------------------------------------
// MFMA flash attention (causal; Q pre-scaled by 0.2 in QKV epilogue).
// QBLK=128 (8 waves x 16 q-rows, 512 thr), KVBLK=128, 2-phase reg-prefetch.
// LDS 64KB: K 128x128B (16K) + Vt 64x256B (16K) + P 8 waves x 16x256B (32K).
// Q: bf16 [B,H,S,HD] (prescaled). K: bf16 [B,H,S,HD]. Vt: bf16 [B,H,HD,S].
// ctx out bf16 [B,S,D].
// ---------------------------------------------------------------------------
__global__ __launch_bounds__(512) void attn_mfma(const u16* __restrict__ Q,
                                                 const u16* __restrict__ K,
                                                 const u16* __restrict__ Vt,
                                                 u16* __restrict__ ctx) {
    __shared__ u32x4 smemv[4096];        // 64 KB
    char* smem = (char*)smemv;
    char* Ksm = smem;                    // 16KB: 128 key-rows x 128B, swizzled
    char* Vsm = smem + 16384;            // 16KB: 64 dim-rows x 256B, swizzled
    const int qb = blockIdx.x;           // 0..15 (128 q rows each)
    const int h  = blockIdx.y;
    const int b  = blockIdx.z;
    const int t  = threadIdx.x;
    const int w  = t >> 6;               // 0..7
    const int l  = t & 63;
    const int g  = l >> 4;
    const int q15 = l & 15;
    char* Psm = smem + 32768 + w*4096;   // per-wave 16 rows(q) x 256B

    const size_t bh = ((size_t)b*HH + h) * SS;
    const u16* Qw = Q + (bh + (size_t)qb*128 + w*16 + q15) * HD;
    s16x8 qf0 = *(const s16x8*)(Qw + g*8);
    s16x8 qf1 = *(const s16x8*)(Qw + 32 + g*8);

    const u16* Kg = K  + bh * HD;
    const u16* Vg = Vt + ((size_t)(b*HH + h)) * HD * SS;

    f32x4 acc[4] = {};                   // acc[n][r]: ctx[q=w*16+4g+r][d=n*16+q15]
    float m = -1e30f, lsum = 0.f;
    const int qg = qb*128 + w*16 + q15;

    // prologue: load tile 0 into regs, write LDS
    u32x4 kreg[2], vreg[2];
    #pragma unroll
    for (int u = 0; u < 2; ++u) {
        int idx = u*512 + t;
        kreg[u] = *(const u32x4*)(Kg + (size_t)(idx >> 3)*HD + (idx & 7)*8);
        vreg[u] = *(const u32x4*)(Vg + (size_t)(idx >> 4)*SS + (idx & 15)*8);
    }
    #pragma unroll
    for (int u = 0; u < 2; ++u) {
        int idx = u*512 + t;
        int kr = idx >> 3, kc = (idx & 7) << 4;
        *(u32x4*)(Ksm + kr*128 + (kc ^ ((kr & 7) << 4))) = kreg[u];
        int vr = idx >> 4, vc = (idx & 15) << 4;
        *(u32x4*)(Vsm + vr*256 + (vc ^ ((vr & 7) << 4))) = vreg[u];
    }

    for (int kt = 0; kt <= qb; ++kt) {
        __syncthreads();                 // tile kt visible in LDS
        const bool pf = (kt < qb);
        if (pf) {                        // issue next tile's loads early (T14)
            #pragma unroll
            for (int u = 0; u < 2; ++u) {
                int idx = u*512 + t;
                kreg[u] = *(const u32x4*)(Kg + (size_t)((kt+1)*128 + (idx >> 3))*HD + (idx & 7)*8);
                vreg[u] = *(const u32x4*)(Vg + (size_t)(idx >> 4)*SS + (kt+1)*128 + (idx & 15)*8);
            }
        }

        // ---- S^T = K . Q^T : 8 key-blocks x 2 k-frags
        f32x4 st[8];
        #pragma unroll
        for (int kb = 0; kb < 8; ++kb) {
            f32x4 z = {0.f, 0.f, 0.f, 0.f};
            int row = kb*16 + q15;
            int sw  = (row & 7) << 4;
            s16x8 a0 = *(const s16x8*)(Ksm + row*128 + ((g*16)      ^ sw));
            s16x8 a1 = *(const s16x8*)(Ksm + row*128 + ((64 + g*16) ^ sw));
            z = __builtin_amdgcn_mfma_f32_16x16x32_bf16(a0, qf0, z, 0, 0, 0);
            z = __builtin_amdgcn_mfma_f32_16x16x32_bf16(a1, qf1, z, 0, 0, 0);
            st[kb] = z;   // st[kb][r] = S[q=q15][key = kt*128 + kb*16 + 4g + r]
        }

        if (kt == qb) {                  // causal mask on diagonal block
            #pragma unroll
            for (int kb = 0; kb < 8; ++kb)
                #pragma unroll
                for (int r = 0; r < 4; ++r) {
                    int key = kt*128 + kb*16 + g*4 + r;
                    if (key > qg) st[kb][r] = -1e30f;
                }
        }

        // ---- online softmax (per q = q15; partners at lane^16, lane^32)
        float tmax = -1e30f;
        #pragma unroll
        for (int kb = 0; kb < 8; ++kb)
            #pragma unroll
            for (int r = 0; r < 4; ++r) tmax = fmaxf(tmax, st[kb][r]);
        tmax = fmaxf(tmax, __shfl_xor(tmax, 16));
        tmax = fmaxf(tmax, __shfl_xor(tmax, 32));
        float mnew = fmaxf(m, tmax);
        float scl  = __expf(m - mnew);
        float ps = 0.f;
        #pragma unroll
        for (int kb = 0; kb < 8; ++kb)
            #pragma unroll
            for (int r = 0; r < 4; ++r) {
                float p = __expf(st[kb][r] - mnew);
                st[kb][r] = p;
                ps += p;
            }
        ps += __shfl_xor(ps, 16);
        ps += __shfl_xor(ps, 32);
        lsum = lsum * scl + ps;
        m = mnew;

        #pragma unroll
        for (int r = 0; r < 4; ++r) {
            float sr = __shfl(scl, g*4 + r);
            #pragma unroll
            for (int n = 0; n < 4; ++n) acc[n][r] *= sr;
        }

        // ---- P -> per-wave LDS (bf16, swizzled 256B rows), then PV
        {
            int swp = (q15 & 7) << 4;
            #pragma unroll
            for (int kb = 0; kb < 8; ++kb) {
                u16x4 pk;
                pk[0] = f2bf(st[kb][0]); pk[1] = f2bf(st[kb][1]);
                pk[2] = f2bf(st[kb][2]); pk[3] = f2bf(st[kb][3]);
                *(u16x4*)(Psm + q15*256 + ((kb*32 + g*8) ^ swp)) = pk;
            }
            s16x8 pa[4];
            #pragma unroll
            for (int c = 0; c < 4; ++c)
                pa[c] = *(const s16x8*)(Psm + q15*256 + ((c*64 + g*16) ^ swp));
            #pragma unroll
            for (int n = 0; n < 4; ++n) {
                int row = n*16 + q15;
                int sw  = (row & 7) << 4;
                #pragma unroll
                for (int c = 0; c < 4; ++c) {
                    s16x8 vv = *(const s16x8*)(Vsm + row*256 + ((c*64 + g*16) ^ sw));
                    acc[n] = __builtin_amdgcn_mfma_f32_16x16x32_bf16(pa[c], vv, acc[n], 0, 0, 0);
                }
            }
        }
        __syncthreads();                 // compute done; LDS free for next tile
        if (pf) {
            #pragma unroll
            for (int u = 0; u < 2; ++u) {
                int idx = u*512 + t;
                int kr = idx >> 3, kc = (idx & 7) << 4;
                *(u32x4*)(Ksm + kr*128 + (kc ^ ((kr & 7) << 4))) = kreg[u];
                int vr = idx >> 4, vc = (idx & 15) << 4;
                *(u32x4*)(Vsm + vr*256 + (vc ^ ((vr & 7) << 4))) = vreg[u];
            }
        }
    }

    // ---- epilogue: normalize, write ctx bf16 [B,S,D]
    #pragma unroll
    for (int r = 0; r < 4; ++r) {
        float inv = 1.f / __shfl(lsum, g*4 + r);
        int qrow = qb*128 + w*16 + g*4 + r;
        u16* crow = ctx + ((size_t)b*SS + qrow)*DD + h*HD;
        #pragma unroll
        for (int n = 0; n < 4; ++n)
            crow[n*16 + q15] = f2bf(acc[n][r] * inv);
    }
}

extern "C" void kernel_launch(void* const* d_in, const int* in_sizes, int n_in,
                              void* d_out, int out_size, void* d_ws, size_t ws_size,
                              hipStream_t stream) {
    const float* x  = (const float*)d_in[0];
    const float* Wq = (const float*)d_in[1];
    const float* Wk = (const float*)d_in[2];
    const float* Wv = (const float*)d_in[3];
    const float* Wo = (const float*)d_in[4];
    const float* bo = (const float*)d_in[5];
    float* out = (float*)d_out;

    const size_t NELT = (size_t)MM * DD;          // 4M
    const size_t NW   = (size_t)1024 * 1024;      // 1M per weight
    u16* wsb  = (u16*)d_ws;
    u16* xb   = wsb;                    // 4M  bf16 x
    u16* WT   = wsb + NELT;             // 4x1M bf16 W^T (q,k,v,o)
    u16* Qb   = wsb + NELT + 4*NW;      // 4M
    u16* Kb   = Qb + NELT;              // 4M
    u16* Vtb  = Kb + NELT;              // 4M
    u16* Ctxb = Vtb + NELT;             // 4M
    u16* WTqkv = WT;
    u16* WTo   = WT + 3*NW;

    hipLaunchKernelGGL(conv_x, dim3(2048), dim3(256), 0, stream, x, xb);
    hipLaunchKernelGGL(conv_wt, dim3(16,16,4), dim3(256), 0, stream, Wq, Wk, Wv, Wo, WT);

    hipLaunchKernelGGL((mfma_gemm<0,4>), dim3(24,32), dim3(256), 0, stream,
                       xb, WTqkv, nullptr, Qb, Kb, Vtb, nullptr);

    hipLaunchKernelGGL(attn_mfma, dim3(16,16,2), dim3(512), 0, stream, Qb, Kb, Vtb, Ctxb);

    hipLaunchKernelGGL((mfma_gemm<1,2>), dim3(16,32), dim3(256), 0, stream,
                       Ctxb, WTo, bo, nullptr, nullptr, nullptr, out);
}

// Round 7
// 122.493 us; speedup vs baseline: 12.3163x; 1.2978x over previous
//
#include <hip/hip_runtime.h>
#include <math.h>

#define BB 2
#define SS 2048
#define DD 1024
#define HH 16
#define HD 64
#define MM (BB*SS)   // 4096

typedef float  f32x4 __attribute__((ext_vector_type(4)));
typedef short  s16x8 __attribute__((ext_vector_type(8)));
typedef unsigned short u16;
typedef u16    u16x4 __attribute__((ext_vector_type(4)));
typedef unsigned int u32;
typedef u32    u32x4 __attribute__((ext_vector_type(4)));

static __device__ __forceinline__ u16 f2bf(float f) {
    u32 u = __float_as_uint(f);
    u = (u + 0x7FFFu + ((u >> 16) & 1u)) >> 16;   // RNE
    return (u16)u;
}

// ---------------------------------------------------------------------------
// x fp32 [4096][1024] -> bf16 (row-major unchanged)
// ---------------------------------------------------------------------------
__global__ __launch_bounds__(256) void conv_x(const float* __restrict__ in,
                                              u16* __restrict__ outb) {
    int i = blockIdx.x * 256 + threadIdx.x;      // each handles 8 elements
    const f32x4* p = (const f32x4*)in;
    f32x4 a = p[i*2], b = p[i*2 + 1];
    u16x4 lo, hi;
    lo[0]=f2bf(a.x); lo[1]=f2bf(a.y); lo[2]=f2bf(a.z); lo[3]=f2bf(a.w);
    hi[0]=f2bf(b.x); hi[1]=f2bf(b.y); hi[2]=f2bf(b.z); hi[3]=f2bf(b.w);
    *(u16x4*)(outb + (size_t)i*8)     = lo;
    *(u16x4*)(outb + (size_t)i*8 + 4) = hi;
}

// ---------------------------------------------------------------------------
// W fp32 [K=1024][N=1024] -> W^T bf16 [N][K].  z selects one of 4 weights.
// Load: 4 passes. Writeback: ONE pass (256 thr x 16 u16 = 64x64 tile).
// ---------------------------------------------------------------------------
__global__ __launch_bounds__(256) void conv_wt(const float* __restrict__ W0,
                                               const float* __restrict__ W1,
                                               const float* __restrict__ W2,
                                               const float* __restrict__ W3,
                                               u16* __restrict__ WT) {
    const int z = blockIdx.z;
    const float* W = (z==0) ? W0 : (z==1) ? W1 : (z==2) ? W2 : W3;
    u16* dst = WT + (size_t)z * 1024 * 1024;
    __shared__ u16 tr[64][72];
    const int t = threadIdx.x;
    const int r0 = blockIdx.y * 64, c0 = blockIdx.x * 64;
    #pragma unroll
    for (int u = 0; u < 4; ++u) {
        int idx = u*256 + t;
        int r = idx >> 4, c4 = (idx & 15) * 4;
        f32x4 v = *(const f32x4*)(W + (size_t)(r0 + r)*1024 + c0 + c4);
        tr[c4+0][r] = f2bf(v.x);
        tr[c4+1][r] = f2bf(v.y);
        tr[c4+2][r] = f2bf(v.z);
        tr[c4+3][r] = f2bf(v.w);
    }
    __syncthreads();
    {
        int c = t >> 2, rq = (t & 3) * 16;       // c: 0..63, rq: 0,16,32,48
        u32x4 v0 = *(const u32x4*)&tr[c][rq];
        u32x4 v1 = *(const u32x4*)&tr[c][rq + 8];
        u16* op = dst + (size_t)(c0 + c)*1024 + r0 + rq;
        *(u32x4*)op       = v0;
        *(u32x4*)(op + 8) = v1;
    }
}

// ---------------------------------------------------------------------------
// bf16 MFMA GEMM: C[M,N] = A[M,1024] @ WT[N,1024]^T.  BM=128, BK=64, BN=NJ*32.
// 256 thr = 4 waves (2x2), wave tile 64 x NJ*16, 16x16x32 MFMA.
// Staging: global -> regs (u32x4) -> XOR-swizzled ds_write.
// EPI 0: QKV epilogue -> Qb(bf16,*0.2,[B,H,S,HD]), Kb(same), Vt(bf16,[B,H,HD,S])
// EPI 1: fp32 out [M][1024] + bias
// ---------------------------------------------------------------------------
template<int EPI, int NJ>
__global__ __launch_bounds__(256) void mfma_gemm(const u16* __restrict__ A,
                                                 const u16* __restrict__ WT,
                                                 const float* __restrict__ bias,
                                                 u16* __restrict__ Qb,
                                                 u16* __restrict__ Kb,
                                                 u16* __restrict__ Vtb,
                                                 float* __restrict__ outF) {
    constexpr int BN = NJ * 32;
    __shared__ u32x4 smemv[2048];                 // 32 KB
    char* smem = (char*)smemv;
    char* Bsm  = smem + 16384;
    const int t   = threadIdx.x;
    const int w   = t >> 6;
    const int l   = t & 63;
    const int c15 = l & 15;
    const int g16 = ((l >> 4) & 3) << 4;          // byte offset of k-group
    const int mw  = w >> 1, nw = w & 1;
    const int brow = blockIdx.y * 128;
    const int bcol = blockIdx.x * BN;

    f32x4 acc[4][NJ] = {};

    const u16* Asrc = A  + (size_t)brow * DD;
    const u16* Bsrc = WT + (size_t)bcol * DD;

    for (int k0 = 0; k0 < DD; k0 += 64) {
        u32x4 av[4], bv[NJ];
        #pragma unroll
        for (int u = 0; u < 4; ++u) {             // A tile: 128 rows x 64 k
            int idx = u*256 + t;
            int row = idx >> 3;
            int ce  = (idx & 7) << 3;             // element offset in row
            av[u] = *(const u32x4*)(Asrc + (size_t)row*DD + k0 + ce);
        }
        #pragma unroll
        for (int u = 0; u < NJ; ++u) {            // B tile: BN rows x 64 k
            int idx = u*256 + t;
            int row = idx >> 3;
            int ce  = (idx & 7) << 3;
            bv[u] = *(const u32x4*)(Bsrc + (size_t)row*DD + k0 + ce);
        }
        #pragma unroll
        for (int u = 0; u < 4; ++u) {
            int idx = u*256 + t;
            int row = idx >> 3;
            int cb  = (idx & 7) << 4;             // byte offset in 128B row
            *(u32x4*)(smem + row*128 + (cb ^ ((row & 7) << 4))) = av[u];
        }
        #pragma unroll
        for (int u = 0; u < NJ; ++u) {
            int idx = u*256 + t;
            int row = idx >> 3;
            int cb  = (idx & 7) << 4;
            *(u32x4*)(Bsm + row*128 + (cb ^ ((row & 7) << 4))) = bv[u];
        }
        __syncthreads();

        s16x8 af[4][2], bf[NJ][2];
        #pragma unroll
        for (int mi = 0; mi < 4; ++mi) {
            int row = mw*64 + mi*16 + c15;
            int sw  = (row & 7) << 4;
            af[mi][0] = *(const s16x8*)(smem + row*128 + ((g16)      ^ sw));
            af[mi][1] = *(const s16x8*)(smem + row*128 + ((64 + g16) ^ sw));
        }
        #pragma unroll
        for (int nj = 0; nj < NJ; ++nj) {
            int row = nw*(NJ*16) + nj*16 + c15;
            int sw  = (row & 7) << 4;
            bf[nj][0] = *(const s16x8*)(Bsm + row*128 + ((g16)      ^ sw));
            bf[nj][1] = *(const s16x8*)(Bsm + row*128 + ((64 + g16) ^ sw));
        }
        #pragma unroll
        for (int c = 0; c < 2; ++c)
            #pragma unroll
            for (int mi = 0; mi < 4; ++mi)
                #pragma unroll
                for (int nj = 0; nj < NJ; ++nj)
                    acc[mi][nj] = __builtin_amdgcn_mfma_f32_16x16x32_bf16(
                        af[mi][c], bf[nj][c], acc[mi][nj], 0, 0, 0);
        __syncthreads();
    }

    if constexpr (EPI == 1) {
        #pragma unroll
        for (int mi = 0; mi < 4; ++mi)
            #pragma unroll
            for (int r = 0; r < 4; ++r) {
                int mg = brow + mw*64 + mi*16 + ((l >> 4) & 3)*4 + r;
                #pragma unroll
                for (int nj = 0; nj < NJ; ++nj) {
                    int nc = bcol + nw*(NJ*16) + nj*16 + c15;
                    outF[(size_t)mg*DD + nc] = acc[mi][nj][r] + bias[nc];
                }
            }
    } else {
        const int wq   = blockIdx.x >> 3;                  // 0=Q, 1=K, 2=V
        const int ncw0 = (blockIdx.x & 7)*128 + nw*64;     // within-weight col base
        if (wq < 2) {
            u16* dst  = wq ? Kb : Qb;
            float scl = wq ? 1.0f : 0.2f;
            #pragma unroll
            for (int mi = 0; mi < 4; ++mi)
                #pragma unroll
                for (int r = 0; r < 4; ++r) {
                    int mg = brow + mw*64 + mi*16 + ((l >> 4) & 3)*4 + r;
                    int b_ = mg >> 11, s_ = mg & (SS-1);
                    #pragma unroll
                    for (int nj = 0; nj < NJ; ++nj) {
                        int nc = ncw0 + nj*16 + c15;
                        int h_ = nc >> 6, d_ = nc & 63;
                        dst[(((size_t)b_*HH + h_)*SS + s_)*HD + d_] =
                            f2bf(acc[mi][nj][r] * scl);
                    }
                }
        } else {
            // V: transpose 64x64 per wave via LDS -> Vt [B,H,HD,S]
            char* tw = smem + w*8192;
            #pragma unroll
            for (int nj = 0; nj < NJ; ++nj)
                #pragma unroll
                for (int mi = 0; mi < 4; ++mi)
                    #pragma unroll
                    for (int r = 0; r < 4; ++r) {
                        int n = nj*16 + c15;
                        int m = mi*16 + ((l >> 4) & 3)*4 + r;
                        *(u16*)(tw + n*128 + ((m*2) ^ ((n & 7) << 4))) =
                            f2bf(acc[mi][nj][r]);
                    }
            __syncthreads();
            #pragma unroll
            for (int it = 0; it < 8; ++it) {
                int n  = it*8 + (l >> 3);
                int mb = l & 7;
                u32x4 v = *(const u32x4*)(tw + n*128 + ((mb*16) ^ ((n & 7) << 4)));
                int nc = ncw0 + n;
                int h_ = nc >> 6, d_ = nc & 63;
                int mg0 = brow + mw*64;
                int b_ = mg0 >> 11;
                int sb = (mg0 & (SS-1)) + mb*8;
                *(u32x4*)(Vtb + (((size_t)b_*HH + h_)*HD + d_)*SS + sb) = v;
            }
        }
    }
}

// ---------------------------------------------------------------------------
// MFMA flash attention (causal; Q pre-scaled by 0.2 in QKV epilogue).
// QBLK=128 (8 waves x 16 q-rows, 512 thr), KVBLK=128, 2-phase reg-prefetch.
// ANTIDIAGONAL PAIRING: block p handles q-tiles p and 15-p sequentially ->
// every block does exactly 17 KV-tile-units; grid = 256 = 1 block/CU,
// perfectly balanced (kills the causal tail that capped round 6).
// LDS 64KB: K 128x128B (16K) + Vt 64x256B (16K) + P 8 waves x 16x256B (32K).
// ---------------------------------------------------------------------------
__global__ __launch_bounds__(512) void attn_mfma(const u16* __restrict__ Q,
                                                 const u16* __restrict__ K,
                                                 const u16* __restrict__ Vt,
                                                 u16* __restrict__ ctx) {
    __shared__ u32x4 smemv[4096];        // 64 KB
    char* smem = (char*)smemv;
    char* Ksm = smem;                    // 16KB: 128 key-rows x 128B, swizzled
    char* Vsm = smem + 16384;            // 16KB: 64 dim-rows x 256B, swizzled
    const int pr = blockIdx.x;           // 0..7 (pair index)
    const int h  = blockIdx.y;
    const int b  = blockIdx.z;
    const int t  = threadIdx.x;
    const int w  = t >> 6;               // 0..7
    const int l  = t & 63;
    const int g  = l >> 4;
    const int q15 = l & 15;
    char* Psm = smem + 32768 + w*4096;   // per-wave 16 rows(q) x 256B

    const size_t bh = ((size_t)b*HH + h) * SS;
    const u16* Kg = K  + bh * HD;
    const u16* Vg = Vt + ((size_t)(b*HH + h)) * HD * SS;

    #pragma unroll 1
    for (int half = 0; half < 2; ++half) {
        const int qb = half ? (15 - pr) : pr;
        const u16* Qw = Q + (bh + (size_t)qb*128 + w*16 + q15) * HD;
        s16x8 qf0 = *(const s16x8*)(Qw + g*8);
        s16x8 qf1 = *(const s16x8*)(Qw + 32 + g*8);

        f32x4 acc[4] = {};               // acc[n][r]: ctx[q=w*16+4g+r][d=n*16+q15]
        float m = -1e30f, lsum = 0.f;
        const int qg = qb*128 + w*16 + q15;

        // prologue: load tile 0 into regs, write LDS
        // (safe: all waves passed the previous half's final barrier, and no
        //  LDS reads happen after it — only register epilogue.)
        u32x4 kreg[2], vreg[2];
        #pragma unroll
        for (int u = 0; u < 2; ++u) {
            int idx = u*512 + t;
            kreg[u] = *(const u32x4*)(Kg + (size_t)(idx >> 3)*HD + (idx & 7)*8);
            vreg[u] = *(const u32x4*)(Vg + (size_t)(idx >> 4)*SS + (idx & 15)*8);
        }
        #pragma unroll
        for (int u = 0; u < 2; ++u) {
            int idx = u*512 + t;
            int kr = idx >> 3, kc = (idx & 7) << 4;
            *(u32x4*)(Ksm + kr*128 + (kc ^ ((kr & 7) << 4))) = kreg[u];
            int vr = idx >> 4, vc = (idx & 15) << 4;
            *(u32x4*)(Vsm + vr*256 + (vc ^ ((vr & 7) << 4))) = vreg[u];
        }

        for (int kt = 0; kt <= qb; ++kt) {
            __syncthreads();             // tile kt visible in LDS
            const bool pf = (kt < qb);
            if (pf) {                    // issue next tile's loads early (T14)
                #pragma unroll
                for (int u = 0; u < 2; ++u) {
                    int idx = u*512 + t;
                    kreg[u] = *(const u32x4*)(Kg + (size_t)((kt+1)*128 + (idx >> 3))*HD + (idx & 7)*8);
                    vreg[u] = *(const u32x4*)(Vg + (size_t)(idx >> 4)*SS + (kt+1)*128 + (idx & 15)*8);
                }
            }

            // ---- S^T = K . Q^T : 8 key-blocks x 2 k-frags
            f32x4 st[8];
            #pragma unroll
            for (int kb = 0; kb < 8; ++kb) {
                f32x4 z = {0.f, 0.f, 0.f, 0.f};
                int row = kb*16 + q15;
                int sw  = (row & 7) << 4;
                s16x8 a0 = *(const s16x8*)(Ksm + row*128 + ((g*16)      ^ sw));
                s16x8 a1 = *(const s16x8*)(Ksm + row*128 + ((64 + g*16) ^ sw));
                z = __builtin_amdgcn_mfma_f32_16x16x32_bf16(a0, qf0, z, 0, 0, 0);
                z = __builtin_amdgcn_mfma_f32_16x16x32_bf16(a1, qf1, z, 0, 0, 0);
                st[kb] = z;   // st[kb][r] = S[q=q15][key = kt*128 + kb*16 + 4g + r]
            }

            if (kt == qb) {              // causal mask on diagonal block
                #pragma unroll
                for (int kb = 0; kb < 8; ++kb)
                    #pragma unroll
                    for (int r = 0; r < 4; ++r) {
                        int key = kt*128 + kb*16 + g*4 + r;
                        if (key > qg) st[kb][r] = -1e30f;
                    }
            }

            // ---- online softmax (per q = q15; partners at lane^16, lane^32)
            float tmax = -1e30f;
            #pragma unroll
            for (int kb = 0; kb < 8; ++kb)
                #pragma unroll
                for (int r = 0; r < 4; ++r) tmax = fmaxf(tmax, st[kb][r]);
            tmax = fmaxf(tmax, __shfl_xor(tmax, 16));
            tmax = fmaxf(tmax, __shfl_xor(tmax, 32));
            float mnew = fmaxf(m, tmax);
            float scl  = __expf(m - mnew);
            float ps = 0.f;
            #pragma unroll
            for (int kb = 0; kb < 8; ++kb)
                #pragma unroll
                for (int r = 0; r < 4; ++r) {
                    float p = __expf(st[kb][r] - mnew);
                    st[kb][r] = p;
                    ps += p;
                }
            ps += __shfl_xor(ps, 16);
            ps += __shfl_xor(ps, 32);
            lsum = lsum * scl + ps;
            m = mnew;

            #pragma unroll
            for (int r = 0; r < 4; ++r) {
                float sr = __shfl(scl, g*4 + r);
                #pragma unroll
                for (int n = 0; n < 4; ++n) acc[n][r] *= sr;
            }

            // ---- P -> per-wave LDS (bf16, swizzled 256B rows), then PV
            {
                int swp = (q15 & 7) << 4;
                #pragma unroll
                for (int kb = 0; kb < 8; ++kb) {
                    u16x4 pk;
                    pk[0] = f2bf(st[kb][0]); pk[1] = f2bf(st[kb][1]);
                    pk[2] = f2bf(st[kb][2]); pk[3] = f2bf(st[kb][3]);
                    *(u16x4*)(Psm + q15*256 + ((kb*32 + g*8) ^ swp)) = pk;
                }
                s16x8 pa[4];
                #pragma unroll
                for (int c = 0; c < 4; ++c)
                    pa[c] = *(const s16x8*)(Psm + q15*256 + ((c*64 + g*16) ^ swp));
                #pragma unroll
                for (int n = 0; n < 4; ++n) {
                    int row = n*16 + q15;
                    int sw  = (row & 7) << 4;
                    #pragma unroll
                    for (int c = 0; c < 4; ++c) {
                        s16x8 vv = *(const s16x8*)(Vsm + row*256 + ((c*64 + g*16) ^ sw));
                        acc[n] = __builtin_amdgcn_mfma_f32_16x16x32_bf16(pa[c], vv, acc[n], 0, 0, 0);
                    }
                }
            }
            __syncthreads();             // compute done; LDS free for next tile
            if (pf) {
                #pragma unroll
                for (int u = 0; u < 2; ++u) {
                    int idx = u*512 + t;
                    int kr = idx >> 3, kc = (idx & 7) << 4;
                    *(u32x4*)(Ksm + kr*128 + (kc ^ ((kr & 7) << 4))) = kreg[u];
                    int vr = idx >> 4, vc = (idx & 15) << 4;
                    *(u32x4*)(Vsm + vr*256 + (vc ^ ((vr & 7) << 4))) = vreg[u];
                }
            }
        }

        // ---- epilogue: normalize, write ctx bf16 [B,S,D]
        #pragma unroll
        for (int r = 0; r < 4; ++r) {
            float inv = 1.f / __shfl(lsum, g*4 + r);
            int qrow = qb*128 + w*16 + g*4 + r;
            u16* crow = ctx + ((size_t)b*SS + qrow)*DD + h*HD;
            #pragma unroll
            for (int n = 0; n < 4; ++n)
                crow[n*16 + q15] = f2bf(acc[n][r] * inv);
        }
    }
}

extern "C" void kernel_launch(void* const* d_in, const int* in_sizes, int n_in,
                              void* d_out, int out_size, void* d_ws, size_t ws_size,
                              hipStream_t stream) {
    const float* x  = (const float*)d_in[0];
    const float* Wq = (const float*)d_in[1];
    const float* Wk = (const float*)d_in[2];
    const float* Wv = (const float*)d_in[3];
    const float* Wo = (const float*)d_in[4];
    const float* bo = (const float*)d_in[5];
    float* out = (float*)d_out;

    const size_t NELT = (size_t)MM * DD;          // 4M
    const size_t NW   = (size_t)1024 * 1024;      // 1M per weight
    u16* wsb  = (u16*)d_ws;
    u16* xb   = wsb;                    // 4M  bf16 x
    u16* WT   = wsb + NELT;             // 4x1M bf16 W^T (q,k,v,o)
    u16* Qb   = wsb + NELT + 4*NW;      // 4M
    u16* Kb   = Qb + NELT;              // 4M
    u16* Vtb  = Kb + NELT;              // 4M
    u16* Ctxb = Vtb + NELT;             // 4M
    u16* WTqkv = WT;
    u16* WTo   = WT + 3*NW;

    hipLaunchKernelGGL(conv_x, dim3(2048), dim3(256), 0, stream, x, xb);
    hipLaunchKernelGGL(conv_wt, dim3(16,16,4), dim3(256), 0, stream, Wq, Wk, Wv, Wo, WT);

    hipLaunchKernelGGL((mfma_gemm<0,4>), dim3(24,32), dim3(256), 0, stream,
                       xb, WTqkv, nullptr, Qb, Kb, Vtb, nullptr);

    hipLaunchKernelGGL(attn_mfma, dim3(8,16,2), dim3(512), 0, stream, Qb, Kb, Vtb, Ctxb);

    hipLaunchKernelGGL((mfma_gemm<1,2>), dim3(16,32), dim3(256), 0, stream,
                       Ctxb, WTo, bo, nullptr, nullptr, nullptr, out);
}

// Round 8
// 112.194 us; speedup vs baseline: 13.4468x; 1.0918x over previous
//
#include <hip/hip_runtime.h>
#include <math.h>

#define BB 2
#define SS 2048
#define DD 1024
#define HH 16
#define HD 64
#define MM (BB*SS)   // 4096

typedef float  f32x4 __attribute__((ext_vector_type(4)));
typedef short  s16x8 __attribute__((ext_vector_type(8)));
typedef unsigned short u16;
typedef u16    u16x4 __attribute__((ext_vector_type(4)));
typedef unsigned int u32;
typedef u32    u32x2 __attribute__((ext_vector_type(2)));
typedef u32    u32x4 __attribute__((ext_vector_type(4)));

static __device__ __forceinline__ u16 f2bf(float f) {
    u32 u = __float_as_uint(f);
    u = (u + 0x7FFFu + ((u >> 16) & 1u)) >> 16;   // RNE
    return (u16)u;
}

// packed f32x2 -> bf16x2 (RNE), single VALU inst (no builtin on gfx950, m240)
static __device__ __forceinline__ u32 cvtpk_bf16(float lo, float hi) {
    u32 r;
    asm("v_cvt_pk_bf16_f32 %0, %1, %2" : "=v"(r) : "v"(lo), "v"(hi));
    return r;
}

// ---------------------------------------------------------------------------
// x fp32 [4096][1024] -> bf16 (row-major unchanged)
// ---------------------------------------------------------------------------
__global__ __launch_bounds__(256) void conv_x(const float* __restrict__ in,
                                              u16* __restrict__ outb) {
    int i = blockIdx.x * 256 + threadIdx.x;      // each handles 8 elements
    const f32x4* p = (const f32x4*)in;
    f32x4 a = p[i*2], b = p[i*2 + 1];
    u16x4 lo, hi;
    lo[0]=f2bf(a.x); lo[1]=f2bf(a.y); lo[2]=f2bf(a.z); lo[3]=f2bf(a.w);
    hi[0]=f2bf(b.x); hi[1]=f2bf(b.y); hi[2]=f2bf(b.z); hi[3]=f2bf(b.w);
    *(u16x4*)(outb + (size_t)i*8)     = lo;
    *(u16x4*)(outb + (size_t)i*8 + 4) = hi;
}

// ---------------------------------------------------------------------------
// W fp32 [K=1024][N=1024] -> W^T bf16 [N][K].  z selects one of 4 weights.
// Load: 4 passes. Writeback: ONE pass (256 thr x 16 u16 = 64x64 tile).
// ---------------------------------------------------------------------------
__global__ __launch_bounds__(256) void conv_wt(const float* __restrict__ W0,
                                               const float* __restrict__ W1,
                                               const float* __restrict__ W2,
                                               const float* __restrict__ W3,
                                               u16* __restrict__ WT) {
    const int z = blockIdx.z;
    const float* W = (z==0) ? W0 : (z==1) ? W1 : (z==2) ? W2 : W3;
    u16* dst = WT + (size_t)z * 1024 * 1024;
    __shared__ u16 tr[64][72];
    const int t = threadIdx.x;
    const int r0 = blockIdx.y * 64, c0 = blockIdx.x * 64;
    #pragma unroll
    for (int u = 0; u < 4; ++u) {
        int idx = u*256 + t;
        int r = idx >> 4, c4 = (idx & 15) * 4;
        f32x4 v = *(const f32x4*)(W + (size_t)(r0 + r)*1024 + c0 + c4);
        tr[c4+0][r] = f2bf(v.x);
        tr[c4+1][r] = f2bf(v.y);
        tr[c4+2][r] = f2bf(v.z);
        tr[c4+3][r] = f2bf(v.w);
    }
    __syncthreads();
    {
        int c = t >> 2, rq = (t & 3) * 16;       // c: 0..63, rq: 0,16,32,48
        u32x4 v0 = *(const u32x4*)&tr[c][rq];
        u32x4 v1 = *(const u32x4*)&tr[c][rq + 8];
        u16* op = dst + (size_t)(c0 + c)*1024 + r0 + rq;
        *(u32x4*)op       = v0;
        *(u32x4*)(op + 8) = v1;
    }
}

// ---------------------------------------------------------------------------
// bf16 MFMA GEMM: C[M,N] = A[M,1024] @ WT[N,1024]^T.  BM=128, BK=64, BN=NJ*32.
// 256 thr = 4 waves (2x2), wave tile 64 x NJ*16, 16x16x32 MFMA.
// Staging: global -> regs (u32x4) -> XOR-swizzled ds_write.
// EPI 0: QKV epilogue -> Qb(bf16,*0.2*log2e,[B,H,S,HD]), Kb, Vt(bf16,[B,H,HD,S])
// EPI 1: fp32 out [M][1024] + bias
// ---------------------------------------------------------------------------
template<int EPI, int NJ>
__global__ __launch_bounds__(256) void mfma_gemm(const u16* __restrict__ A,
                                                 const u16* __restrict__ WT,
                                                 const float* __restrict__ bias,
                                                 u16* __restrict__ Qb,
                                                 u16* __restrict__ Kb,
                                                 u16* __restrict__ Vtb,
                                                 float* __restrict__ outF) {
    constexpr int BN = NJ * 32;
    __shared__ u32x4 smemv[2048];                 // 32 KB
    char* smem = (char*)smemv;
    char* Bsm  = smem + 16384;
    const int t   = threadIdx.x;
    const int w   = t >> 6;
    const int l   = t & 63;
    const int c15 = l & 15;
    const int g16 = ((l >> 4) & 3) << 4;          // byte offset of k-group
    const int mw  = w >> 1, nw = w & 1;
    const int brow = blockIdx.y * 128;
    const int bcol = blockIdx.x * BN;

    f32x4 acc[4][NJ] = {};

    const u16* Asrc = A  + (size_t)brow * DD;
    const u16* Bsrc = WT + (size_t)bcol * DD;

    for (int k0 = 0; k0 < DD; k0 += 64) {
        u32x4 av[4], bv[NJ];
        #pragma unroll
        for (int u = 0; u < 4; ++u) {             // A tile: 128 rows x 64 k
            int idx = u*256 + t;
            int row = idx >> 3;
            int ce  = (idx & 7) << 3;             // element offset in row
            av[u] = *(const u32x4*)(Asrc + (size_t)row*DD + k0 + ce);
        }
        #pragma unroll
        for (int u = 0; u < NJ; ++u) {            // B tile: BN rows x 64 k
            int idx = u*256 + t;
            int row = idx >> 3;
            int ce  = (idx & 7) << 3;
            bv[u] = *(const u32x4*)(Bsrc + (size_t)row*DD + k0 + ce);
        }
        #pragma unroll
        for (int u = 0; u < 4; ++u) {
            int idx = u*256 + t;
            int row = idx >> 3;
            int cb  = (idx & 7) << 4;             // byte offset in 128B row
            *(u32x4*)(smem + row*128 + (cb ^ ((row & 7) << 4))) = av[u];
        }
        #pragma unroll
        for (int u = 0; u < NJ; ++u) {
            int idx = u*256 + t;
            int row = idx >> 3;
            int cb  = (idx & 7) << 4;
            *(u32x4*)(Bsm + row*128 + (cb ^ ((row & 7) << 4))) = bv[u];
        }
        __syncthreads();

        s16x8 af[4][2], bf[NJ][2];
        #pragma unroll
        for (int mi = 0; mi < 4; ++mi) {
            int row = mw*64 + mi*16 + c15;
            int sw  = (row & 7) << 4;
            af[mi][0] = *(const s16x8*)(smem + row*128 + ((g16)      ^ sw));
            af[mi][1] = *(const s16x8*)(smem + row*128 + ((64 + g16) ^ sw));
        }
        #pragma unroll
        for (int nj = 0; nj < NJ; ++nj) {
            int row = nw*(NJ*16) + nj*16 + c15;
            int sw  = (row & 7) << 4;
            bf[nj][0] = *(const s16x8*)(Bsm + row*128 + ((g16)      ^ sw));
            bf[nj][1] = *(const s16x8*)(Bsm + row*128 + ((64 + g16) ^ sw));
        }
        #pragma unroll
        for (int c = 0; c < 2; ++c)
            #pragma unroll
            for (int mi = 0; mi < 4; ++mi)
                #pragma unroll
                for (int nj = 0; nj < NJ; ++nj)
                    acc[mi][nj] = __builtin_amdgcn_mfma_f32_16x16x32_bf16(
                        af[mi][c], bf[nj][c], acc[mi][nj], 0, 0, 0);
        __syncthreads();
    }

    if constexpr (EPI == 1) {
        #pragma unroll
        for (int mi = 0; mi < 4; ++mi)
            #pragma unroll
            for (int r = 0; r < 4; ++r) {
                int mg = brow + mw*64 + mi*16 + ((l >> 4) & 3)*4 + r;
                #pragma unroll
                for (int nj = 0; nj < NJ; ++nj) {
                    int nc = bcol + nw*(NJ*16) + nj*16 + c15;
                    outF[(size_t)mg*DD + nc] = acc[mi][nj][r] + bias[nc];
                }
            }
    } else {
        const int wq   = blockIdx.x >> 3;                  // 0=Q, 1=K, 2=V
        const int ncw0 = (blockIdx.x & 7)*128 + nw*64;     // within-weight col base
        if (wq < 2) {
            u16* dst  = wq ? Kb : Qb;
            // Q pre-scaled by 0.2*log2(e) so attention softmax runs in exp2 domain
            float scl = wq ? 1.0f : 0.28853900817779268f;
            #pragma unroll
            for (int mi = 0; mi < 4; ++mi)
                #pragma unroll
                for (int r = 0; r < 4; ++r) {
                    int mg = brow + mw*64 + mi*16 + ((l >> 4) & 3)*4 + r;
                    int b_ = mg >> 11, s_ = mg & (SS-1);
                    #pragma unroll
                    for (int nj = 0; nj < NJ; ++nj) {
                        int nc = ncw0 + nj*16 + c15;
                        int h_ = nc >> 6, d_ = nc & 63;
                        dst[(((size_t)b_*HH + h_)*SS + s_)*HD + d_] =
                            f2bf(acc[mi][nj][r] * scl);
                    }
                }
        } else {
            // V: transpose 64x64 per wave via LDS -> Vt [B,H,HD,S]
            char* tw = smem + w*8192;
            #pragma unroll
            for (int nj = 0; nj < NJ; ++nj)
                #pragma unroll
                for (int mi = 0; mi < 4; ++mi)
                    #pragma unroll
                    for (int r = 0; r < 4; ++r) {
                        int n = nj*16 + c15;
                        int m = mi*16 + ((l >> 4) & 3)*4 + r;
                        *(u16*)(tw + n*128 + ((m*2) ^ ((n & 7) << 4))) =
                            f2bf(acc[mi][nj][r]);
                    }
            __syncthreads();
            #pragma unroll
            for (int it = 0; it < 8; ++it) {
                int n  = it*8 + (l >> 3);
                int mb = l & 7;
                u32x4 v = *(const u32x4*)(tw + n*128 + ((mb*16) ^ ((n & 7) << 4)));
                int nc = ncw0 + n;
                int h_ = nc >> 6, d_ = nc & 63;
                int mg0 = brow + mw*64;
                int b_ = mg0 >> 11;
                int sb = (mg0 & (SS-1)) + mb*8;
                *(u32x4*)(Vtb + (((size_t)b_*HH + h_)*HD + d_)*SS + sb) = v;
            }
        }
    }
}

// ---------------------------------------------------------------------------
// MFMA flash attention (causal; Q pre-scaled by 0.2*log2e -> exp2 softmax).
// QBLK=128 (8 waves x 16 q-rows, 512 thr), KVBLK=128.
// Antidiagonal pairing: block p does q-tiles p and 15-p (17 units each).
// K/V DOUBLE-BUFFERED in LDS -> ONE barrier per tile-step; global loads for
// kt+1 issue before the barrier (latency hides under compute, T4/T14 spirit).
// LDS 96KB: K dbuf 2x16K | V dbuf 2x16K | P 8 waves x 4K.
// P pack via v_cvt_pk_bf16_f32; s_setprio(1) around MFMA clusters (T5).
// ---------------------------------------------------------------------------
__global__ __launch_bounds__(512) void attn_mfma(const u16* __restrict__ Q,
                                                 const u16* __restrict__ K,
                                                 const u16* __restrict__ Vt,
                                                 u16* __restrict__ ctx) {
    __shared__ u32x4 smemv[6144];        // 96 KB
    char* smem = (char*)smemv;
    const int pr = blockIdx.x;           // 0..7 (pair index)
    const int h  = blockIdx.y;
    const int b  = blockIdx.z;
    const int t  = threadIdx.x;
    const int w  = t >> 6;               // 0..7
    const int l  = t & 63;
    const int g  = l >> 4;
    const int q15 = l & 15;
    char* Psm = smem + 65536 + w*4096;   // per-wave 16 rows(q) x 256B

    const size_t bh = ((size_t)b*HH + h) * SS;
    const u16* Kg = K  + bh * HD;
    const u16* Vg = Vt + ((size_t)(b*HH + h)) * HD * SS;

    #pragma unroll 1
    for (int half = 0; half < 2; ++half) {
        const int qb = half ? (15 - pr) : pr;
        const u16* Qw = Q + (bh + (size_t)qb*128 + w*16 + q15) * HD;
        s16x8 qf0 = *(const s16x8*)(Qw + g*8);
        s16x8 qf1 = *(const s16x8*)(Qw + 32 + g*8);

        f32x4 acc[4] = {};               // acc[n][r]: ctx[q=w*16+4g+r][d=n*16+q15]
        float m = -1e30f, lsum = 0.f;
        const int qg = qb*128 + w*16 + q15;

        // prologue: load tile 0 into regs, write buf0
        u32x4 kreg[2], vreg[2];
        #pragma unroll
        for (int u = 0; u < 2; ++u) {
            int idx = u*512 + t;
            kreg[u] = *(const u32x4*)(Kg + (size_t)(idx >> 3)*HD + (idx & 7)*8);
            vreg[u] = *(const u32x4*)(Vg + (size_t)(idx >> 4)*SS + (idx & 15)*8);
        }
        if (half) __syncthreads();       // prev half's readers of buf0 done
        #pragma unroll
        for (int u = 0; u < 2; ++u) {
            int idx = u*512 + t;
            int kr = idx >> 3, kc = (idx & 7) << 4;
            *(u32x4*)(smem + kr*128 + (kc ^ ((kr & 7) << 4))) = kreg[u];
            int vr = idx >> 4, vc = (idx & 15) << 4;
            *(u32x4*)(smem + 32768 + vr*256 + (vc ^ ((vr & 7) << 4))) = vreg[u];
        }

        int cur = 0;
        for (int kt = 0; kt <= qb; ++kt) {
            const bool pf = (kt < qb);
            if (pf) {                    // issue next tile's loads BEFORE barrier
                #pragma unroll
                for (int u = 0; u < 2; ++u) {
                    int idx = u*512 + t;
                    kreg[u] = *(const u32x4*)(Kg + (size_t)((kt+1)*128 + (idx >> 3))*HD + (idx & 7)*8);
                    vreg[u] = *(const u32x4*)(Vg + (size_t)(idx >> 4)*SS + (kt+1)*128 + (idx & 15)*8);
                }
            }
            __syncthreads();             // buf[cur] staged; buf[cur^1] readers done
            char* Kc = smem + (cur << 14);
            char* Vc = smem + 32768 + (cur << 14);

            // ---- S^T = K . Q^T : 8 key-blocks x 2 k-frags
            f32x4 st[8];
            __builtin_amdgcn_s_setprio(1);
            #pragma unroll
            for (int kb = 0; kb < 8; ++kb) {
                f32x4 z = {0.f, 0.f, 0.f, 0.f};
                int row = kb*16 + q15;
                int sw  = (row & 7) << 4;
                s16x8 a0 = *(const s16x8*)(Kc + row*128 + ((g*16)      ^ sw));
                s16x8 a1 = *(const s16x8*)(Kc + row*128 + ((64 + g*16) ^ sw));
                z = __builtin_amdgcn_mfma_f32_16x16x32_bf16(a0, qf0, z, 0, 0, 0);
                z = __builtin_amdgcn_mfma_f32_16x16x32_bf16(a1, qf1, z, 0, 0, 0);
                st[kb] = z;   // st[kb][r] = S[q=q15][key = kt*128 + kb*16 + 4g + r]
            }
            __builtin_amdgcn_s_setprio(0);

            if (kt == qb) {              // causal mask on diagonal block
                #pragma unroll
                for (int kb = 0; kb < 8; ++kb)
                    #pragma unroll
                    for (int r = 0; r < 4; ++r) {
                        int key = kt*128 + kb*16 + g*4 + r;
                        if (key > qg) st[kb][r] = -1e30f;
                    }
            }

            // ---- online softmax in exp2 domain (per q=q15; partners ^16, ^32)
            float tmax = -1e30f;
            #pragma unroll
            for (int kb = 0; kb < 8; ++kb)
                #pragma unroll
                for (int r = 0; r < 4; ++r) tmax = fmaxf(tmax, st[kb][r]);
            tmax = fmaxf(tmax, __shfl_xor(tmax, 16));
            tmax = fmaxf(tmax, __shfl_xor(tmax, 32));
            float mnew = fmaxf(m, tmax);
            float scl  = __builtin_amdgcn_exp2f(m - mnew);
            float ps = 0.f;
            #pragma unroll
            for (int kb = 0; kb < 8; ++kb)
                #pragma unroll
                for (int r = 0; r < 4; ++r) {
                    float p = __builtin_amdgcn_exp2f(st[kb][r] - mnew);
                    st[kb][r] = p;
                    ps += p;
                }
            ps += __shfl_xor(ps, 16);
            ps += __shfl_xor(ps, 32);
            lsum = lsum * scl + ps;
            m = mnew;

            #pragma unroll
            for (int r = 0; r < 4; ++r) {
                float sr = __shfl(scl, g*4 + r);
                #pragma unroll
                for (int n = 0; n < 4; ++n) acc[n][r] *= sr;
            }

            // ---- P -> per-wave LDS (packed bf16 via cvt_pk), then PV
            {
                int swp = (q15 & 7) << 4;
                #pragma unroll
                for (int kb = 0; kb < 8; ++kb) {
                    u32x2 pk2;
                    pk2[0] = cvtpk_bf16(st[kb][0], st[kb][1]);
                    pk2[1] = cvtpk_bf16(st[kb][2], st[kb][3]);
                    *(u32x2*)(Psm + q15*256 + ((kb*32 + g*8) ^ swp)) = pk2;
                }
                s16x8 pa[4];
                #pragma unroll
                for (int c = 0; c < 4; ++c)
                    pa[c] = *(const s16x8*)(Psm + q15*256 + ((c*64 + g*16) ^ swp));
                __builtin_amdgcn_s_setprio(1);
                #pragma unroll
                for (int n = 0; n < 4; ++n) {
                    int row = n*16 + q15;
                    int sw  = (row & 7) << 4;
                    #pragma unroll
                    for (int c = 0; c < 4; ++c) {
                        s16x8 vv = *(const s16x8*)(Vc + row*256 + ((c*64 + g*16) ^ sw));
                        acc[n] = __builtin_amdgcn_mfma_f32_16x16x32_bf16(pa[c], vv, acc[n], 0, 0, 0);
                    }
                }
                __builtin_amdgcn_s_setprio(0);
            }

            if (pf) {                    // stage kt+1 into the idle buffer
                char* Kn = smem + ((cur ^ 1) << 14);
                char* Vn = smem + 32768 + ((cur ^ 1) << 14);
                #pragma unroll
                for (int u = 0; u < 2; ++u) {
                    int idx = u*512 + t;
                    int kr = idx >> 3, kc = (idx & 7) << 4;
                    *(u32x4*)(Kn + kr*128 + (kc ^ ((kr & 7) << 4))) = kreg[u];
                    int vr = idx >> 4, vc = (idx & 15) << 4;
                    *(u32x4*)(Vn + vr*256 + (vc ^ ((vr & 7) << 4))) = vreg[u];
                }
            }
            cur ^= 1;
        }

        // ---- epilogue: normalize, write ctx bf16 [B,S,D]
        #pragma unroll
        for (int r = 0; r < 4; ++r) {
            float inv = 1.f / __shfl(lsum, g*4 + r);
            int qrow = qb*128 + w*16 + g*4 + r;
            u16* crow = ctx + ((size_t)b*SS + qrow)*DD + h*HD;
            #pragma unroll
            for (int n = 0; n < 4; ++n)
                crow[n*16 + q15] = f2bf(acc[n][r] * inv);
        }
    }
}

extern "C" void kernel_launch(void* const* d_in, const int* in_sizes, int n_in,
                              void* d_out, int out_size, void* d_ws, size_t ws_size,
                              hipStream_t stream) {
    const float* x  = (const float*)d_in[0];
    const float* Wq = (const float*)d_in[1];
    const float* Wk = (const float*)d_in[2];
    const float* Wv = (const float*)d_in[3];
    const float* Wo = (const float*)d_in[4];
    const float* bo = (const float*)d_in[5];
    float* out = (float*)d_out;

    const size_t NELT = (size_t)MM * DD;          // 4M
    const size_t NW   = (size_t)1024 * 1024;      // 1M per weight
    u16* wsb  = (u16*)d_ws;
    u16* xb   = wsb;                    // 4M  bf16 x
    u16* WT   = wsb + NELT;             // 4x1M bf16 W^T (q,k,v,o)
    u16* Qb   = wsb + NELT + 4*NW;      // 4M
    u16* Kb   = Qb + NELT;              // 4M
    u16* Vtb  = Kb + NELT;              // 4M
    u16* Ctxb = Vtb + NELT;             // 4M
    u16* WTqkv = WT;
    u16* WTo   = WT + 3*NW;

    hipLaunchKernelGGL(conv_x, dim3(2048), dim3(256), 0, stream, x, xb);
    hipLaunchKernelGGL(conv_wt, dim3(16,16,4), dim3(256), 0, stream, Wq, Wk, Wv, Wo, WT);

    hipLaunchKernelGGL((mfma_gemm<0,4>), dim3(24,32), dim3(256), 0, stream,
                       xb, WTqkv, nullptr, Qb, Kb, Vtb, nullptr);

    hipLaunchKernelGGL(attn_mfma, dim3(8,16,2), dim3(512), 0, stream, Qb, Kb, Vtb, Ctxb);

    hipLaunchKernelGGL((mfma_gemm<1,2>), dim3(16,32), dim3(256), 0, stream,
                       Ctxb, WTo, bo, nullptr, nullptr, nullptr, out);
}